// Round 2
// baseline (546.541 us; speedup 1.0000x reference)
//
#include <hip/hip_runtime.h>
#include <cstddef>

#define G_   2048
#define NPG_ 512
#define CPG_ 128
#define CPG2_ 32
#define N0_  (G_*NPG_)
#define M1_  (G_*CPG_)
#define M2_  (G_*CPG2_)

// output layout (floats): z_what[G,64] | z_mask[G,64] | mu[G,128] | sigma[G,128] | f[G,256]
#define OFF_ZW 0
#define OFF_ZM (G_*64)
#define OFF_MU (2*G_*64)
#define OFF_SG (2*G_*64 + G_*128)
#define OFF_F  (2*G_*64 + 2*G_*128)

__device__ __forceinline__ float celu_f(float x)     { return x > 0.f ? x : __expf(x) - 1.f; }
__device__ __forceinline__ float softplus_f(float x) { return fmaxf(x, 0.f) + __logf(1.f + __expf(-fabsf(x))); }

// ---------------- conv1: [N0 edges] -> f1 [M1,32], one block per glimpse ----------------
// agg transposed to [j][lc]: atomic bank = lc&31 (random lc -> ~2-way, free)
__global__ __launch_bounds__(256) void k_conv1(
    const float* __restrict__ rgb, const float* __restrict__ pos, const float* __restrict__ pos1,
    const int* __restrict__ idx0, const float* __restrict__ W1l, const float* __restrict__ b1l,
    const float* __restrict__ W1g, const float* __restrict__ b1g, float* __restrict__ f1)
{
    const int g = blockIdx.x, t = threadIdx.x;
    __shared__ float agg[16*CPG_];    // [j*128 + lc]
    __shared__ float aggT[CPG_*20];   // [lc*20 + j], for b128 reads in global conv
    __shared__ float cnt[CPG_];
    __shared__ float sW1g[512];

    for (int i = t; i < 16*CPG_; i += 256) agg[i] = 0.f;
    if (t < CPG_) cnt[t] = 0.f;
    for (int i = t; i < 512; i += 256) sW1g[i] = W1g[i];

    // uniform weight preload (scalar loads, hoisted)
    float wj[16], wx[16], wy[16], wz[16], bb[16];
    #pragma unroll
    for (int j = 0; j < 16; j++) {
        wj[j] = W1l[j]; wx[j] = W1l[16+j]; wy[j] = W1l[32+j]; wz[j] = W1l[48+j]; bb[j] = b1l[j];
    }
    __syncthreads();

    #pragma unroll
    for (int r = 0; r < 2; r++) {
        const int p  = g*NPG_ + r*256 + t;
        const float x0 = rgb[p];
        const int c  = idx0[p];
        const int lc = c - g*CPG_;
        const float rx = pos[p*3+0] - pos1[c*3+0];
        const float ry = pos[p*3+1] - pos1[c*3+1];
        const float rz = pos[p*3+2] - pos1[c*3+2];
        #pragma unroll
        for (int j = 0; j < 16; j++) {
            const float h = bb[j] + x0*wj[j] + rx*wx[j] + ry*wy[j] + rz*wz[j];
            atomicAdd(&agg[j*CPG_ + lc], celu_f(h));
        }
        atomicAdd(&cnt[lc], 1.f);
    }
    __syncthreads();

    // divide + transpose: agg[j][lc] -> aggT[lc][j]
    #pragma unroll
    for (int ii = 0; ii < 8; ii++) {
        const int idx = t + 256*ii;
        const int lc = idx & 127, j = idx >> 7;
        aggT[lc*20 + j] = agg[j*CPG_ + lc] / fmaxf(cnt[lc], 1.f);
    }
    __syncthreads();

    // global conv: [128,16] @ [16,32] -> celu -> f1
    const int oc = t & 31;
    float wreg[16];
    #pragma unroll
    for (int j = 0; j < 16; j++) wreg[j] = sW1g[j*32 + oc];
    const float bg = b1g[oc];
    #pragma unroll
    for (int i = 0; i < 16; i++) {
        const int lc = (t >> 5) + i*8;
        float a = bg;
        #pragma unroll
        for (int j = 0; j < 16; j += 4) {
            const float4 a4 = *(const float4*)&aggT[lc*20 + j];
            a += a4.x*wreg[j] + a4.y*wreg[j+1] + a4.z*wreg[j+2] + a4.w*wreg[j+3];
        }
        f1[(size_t)(g*CPG_ + lc)*32 + oc] = celu_f(a);
    }
}

// ---------------- conv2: [M1 edges] -> f2 [M2,128], one block per glimpse ----------------
// register tiles: local 4 edges x 8 ch / thread; global 4 rows x 4 ch / thread
__global__ __launch_bounds__(256) void k_conv2(
    const float* __restrict__ f1, const float* __restrict__ pos1, const float* __restrict__ pos2,
    const int* __restrict__ idx1, const float* __restrict__ W2l, const float* __restrict__ b2l,
    const float* __restrict__ W2g, const float* __restrict__ b2g, float* __restrict__ f2)
{
    const int g = blockIdx.x, t = threadIdx.x;
    __shared__ float sW2l[35*64];
    __shared__ float xs[CPG_*36];     // 35 inputs + pad; bank(36e+k)=(4e+k)&31
    __shared__ int   slc[CPG_];
    __shared__ float aggt[64*33];     // atomic target: [ch*33 + slc] (slc randomizes bank)
    __shared__ float aggr[32*68];     // [r*68 + ch] for b128 reads in global conv
    __shared__ float cnt[CPG2_];

    for (int i = t; i < 2240; i += 256) sW2l[i] = W2l[i];
    for (int i = t; i < 64*33; i += 256) aggt[i] = 0.f;
    if (t < CPG2_) cnt[t] = 0.f;
    {   // f1 tile: 4096 floats, vectorized
        const int row = t >> 1, col = (t & 1) * 16;
        #pragma unroll
        for (int q = 0; q < 4; q++) {
            const float4 v = *(const float4*)&f1[(size_t)g*4096 + t*16 + q*4];
            *(float4*)&xs[row*36 + col + q*4] = v;
        }
    }
    if (t < CPG_) {
        const int c2 = idx1[g*CPG_ + t];
        slc[t] = c2 - g*CPG2_;
        #pragma unroll
        for (int d = 0; d < 3; d++)
            xs[t*36 + 32 + d] = pos1[(g*CPG_ + t)*3 + d] - pos2[c2*3 + d];
        xs[t*36 + 35] = 0.f;
    }
    __syncthreads();

    // local conv: thread tile = edges {eg+32i} x ch [8cg, 8cg+8)
    const int cg = t & 7, eg = t >> 3;
    const int ch0 = cg * 8;
    float acc[4][8];
    {
        const float4 bA = *(const float4*)&b2l[ch0];
        const float4 bB = *(const float4*)&b2l[ch0+4];
        #pragma unroll
        for (int i = 0; i < 4; i++) {
            acc[i][0]=bA.x; acc[i][1]=bA.y; acc[i][2]=bA.z; acc[i][3]=bA.w;
            acc[i][4]=bB.x; acc[i][5]=bB.y; acc[i][6]=bB.z; acc[i][7]=bB.w;
        }
    }
    #pragma unroll
    for (int kq = 0; kq < 8; kq++) {
        const int k = kq*4;
        float w[4][8];
        #pragma unroll
        for (int dk = 0; dk < 4; dk++) {
            const float4 a = *(const float4*)&sW2l[(k+dk)*64 + ch0];
            const float4 b = *(const float4*)&sW2l[(k+dk)*64 + ch0 + 4];
            w[dk][0]=a.x; w[dk][1]=a.y; w[dk][2]=a.z; w[dk][3]=a.w;
            w[dk][4]=b.x; w[dk][5]=b.y; w[dk][6]=b.z; w[dk][7]=b.w;
        }
        #pragma unroll
        for (int i = 0; i < 4; i++) {
            const float4 x4 = *(const float4*)&xs[(eg + 32*i)*36 + k];
            #pragma unroll
            for (int j = 0; j < 8; j++)
                acc[i][j] += x4.x*w[0][j] + x4.y*w[1][j] + x4.z*w[2][j] + x4.w*w[3][j];
        }
    }
    {   // tail k = 32..34
        float w[3][8];
        #pragma unroll
        for (int dk = 0; dk < 3; dk++) {
            const float4 a = *(const float4*)&sW2l[(32+dk)*64 + ch0];
            const float4 b = *(const float4*)&sW2l[(32+dk)*64 + ch0 + 4];
            w[dk][0]=a.x; w[dk][1]=a.y; w[dk][2]=a.z; w[dk][3]=a.w;
            w[dk][4]=b.x; w[dk][5]=b.y; w[dk][6]=b.z; w[dk][7]=b.w;
        }
        #pragma unroll
        for (int i = 0; i < 4; i++) {
            const float4 x4 = *(const float4*)&xs[(eg + 32*i)*36 + 32];
            #pragma unroll
            for (int j = 0; j < 8; j++)
                acc[i][j] += x4.x*w[0][j] + x4.y*w[1][j] + x4.z*w[2][j];
        }
    }
    #pragma unroll
    for (int i = 0; i < 4; i++) {
        const int s = slc[eg + 32*i];
        #pragma unroll
        for (int j = 0; j < 8; j++)
            atomicAdd(&aggt[(ch0 + j)*33 + s], celu_f(acc[i][j]));
    }
    if (t < CPG_) atomicAdd(&cnt[slc[t]], 1.f);
    __syncthreads();

    // divide + transpose aggt[ch][r] -> aggr[r][ch]
    #pragma unroll
    for (int ii = 0; ii < 8; ii++) {
        const int idx = t + 256*ii;
        const int r = idx >> 6, ch = idx & 63;
        aggr[r*68 + ch] = aggt[ch*33 + r] / fmaxf(cnt[r], 1.f);
    }
    __syncthreads();

    // global conv: [32,64] @ [64,128]; thread tile = rows {rg+8i} x ch [4cg2, 4cg2+4)
    const int cg2 = t & 31, rg = t >> 5;
    const int co = cg2 * 4;
    float acc2[4][4];
    {
        const float4 b4 = *(const float4*)&b2g[co];
        #pragma unroll
        for (int i = 0; i < 4; i++) { acc2[i][0]=b4.x; acc2[i][1]=b4.y; acc2[i][2]=b4.z; acc2[i][3]=b4.w; }
    }
    #pragma unroll
    for (int kq = 0; kq < 16; kq++) {
        const int k = kq*4;
        const float4 w0 = *(const float4*)&W2g[(k+0)*128 + co];
        const float4 w1 = *(const float4*)&W2g[(k+1)*128 + co];
        const float4 w2 = *(const float4*)&W2g[(k+2)*128 + co];
        const float4 w3 = *(const float4*)&W2g[(k+3)*128 + co];
        #pragma unroll
        for (int i = 0; i < 4; i++) {
            const float4 x4 = *(const float4*)&aggr[(rg + 8*i)*68 + k];
            acc2[i][0] += x4.x*w0.x + x4.y*w1.x + x4.z*w2.x + x4.w*w3.x;
            acc2[i][1] += x4.x*w0.y + x4.y*w1.y + x4.z*w2.y + x4.w*w3.y;
            acc2[i][2] += x4.x*w0.z + x4.y*w1.z + x4.z*w2.z + x4.w*w3.z;
            acc2[i][3] += x4.x*w0.w + x4.y*w1.w + x4.z*w2.w + x4.w*w3.w;
        }
    }
    #pragma unroll
    for (int i = 0; i < 4; i++) {
        const int r = rg + 8*i;
        float4 o;
        o.x = celu_f(acc2[i][0]); o.y = celu_f(acc2[i][1]);
        o.z = celu_f(acc2[i][2]); o.w = celu_f(acc2[i][3]);
        *(float4*)&f2[(size_t)(g*CPG2_ + r)*128 + co] = o;
    }
}

// ---------------- conv3 + linear + sample: 2 glimpses per block ----------------
__global__ __launch_bounds__(256) void k_conv3(
    const float* __restrict__ f2, const float* __restrict__ pos2,
    const float* __restrict__ W3l, const float* __restrict__ b3l,
    const float* __restrict__ W3g, const float* __restrict__ b3g,
    const float* __restrict__ Wlin, const float* __restrict__ blin,
    const float* __restrict__ eps, float* __restrict__ out)
{
    const int g0 = blockIdx.x * 2, t = threadIdx.x;
    __shared__ float xs[64*132];   // 2 glimpses x 32 rows x (128 feat + 3 pos + pad); reused as red
    __shared__ float agg[256];
    __shared__ float f3s[512];
    __shared__ float outs[512];
    float* const red = xs;         // aliased; guarded by __syncthreads

    {   // stage f2 tile: 8192 floats, vectorized
        const int row = t >> 2, col = (t & 3) * 32;
        #pragma unroll
        for (int q = 0; q < 8; q++) {
            const float4 v = *(const float4*)&f2[(size_t)g0*4096 + t*32 + q*4];
            *(float4*)&xs[row*132 + col + q*4] = v;
        }
    }
    if (t < 64) {
        #pragma unroll
        for (int d = 0; d < 3; d++)
            xs[t*132 + 128 + d] = pos2[(g0*CPG2_ + t)*3 + d];
        xs[t*132 + 131] = 0.f;
    }
    __syncthreads();

    // local conv: thread tile = rows {rg+16i} x ch [8cg, 8cg+8), W3l from global (L2)
    const int cg = t & 15, rg = t >> 4;
    const int ch0 = cg * 8;
    float acc[4][8];
    {
        const float4 bA = *(const float4*)&b3l[ch0];
        const float4 bB = *(const float4*)&b3l[ch0+4];
        #pragma unroll
        for (int i = 0; i < 4; i++) {
            acc[i][0]=bA.x; acc[i][1]=bA.y; acc[i][2]=bA.z; acc[i][3]=bA.w;
            acc[i][4]=bB.x; acc[i][5]=bB.y; acc[i][6]=bB.z; acc[i][7]=bB.w;
        }
    }
    #pragma unroll
    for (int kq = 0; kq < 32; kq++) {
        const int k = kq*4;
        float w[4][8];
        #pragma unroll
        for (int dk = 0; dk < 4; dk++) {
            const float4 a = *(const float4*)&W3l[(k+dk)*128 + ch0];
            const float4 b = *(const float4*)&W3l[(k+dk)*128 + ch0 + 4];
            w[dk][0]=a.x; w[dk][1]=a.y; w[dk][2]=a.z; w[dk][3]=a.w;
            w[dk][4]=b.x; w[dk][5]=b.y; w[dk][6]=b.z; w[dk][7]=b.w;
        }
        #pragma unroll
        for (int i = 0; i < 4; i++) {
            const float4 x4 = *(const float4*)&xs[(rg + 16*i)*132 + k];
            #pragma unroll
            for (int j = 0; j < 8; j++)
                acc[i][j] += x4.x*w[0][j] + x4.y*w[1][j] + x4.z*w[2][j] + x4.w*w[3][j];
        }
    }
    {   // tail k = 128..130
        float w[3][8];
        #pragma unroll
        for (int dk = 0; dk < 3; dk++) {
            const float4 a = *(const float4*)&W3l[(128+dk)*128 + ch0];
            const float4 b = *(const float4*)&W3l[(128+dk)*128 + ch0 + 4];
            w[dk][0]=a.x; w[dk][1]=a.y; w[dk][2]=a.z; w[dk][3]=a.w;
            w[dk][4]=b.x; w[dk][5]=b.y; w[dk][6]=b.z; w[dk][7]=b.w;
        }
        #pragma unroll
        for (int i = 0; i < 4; i++) {
            const float4 x4 = *(const float4*)&xs[(rg + 16*i)*132 + 128];
            #pragma unroll
            for (int j = 0; j < 8; j++)
                acc[i][j] += x4.x*w[0][j] + x4.y*w[1][j] + x4.z*w[2][j];
        }
    }
    // celu + partial row-sums: i=0,1 -> glimpse 0 rows {rg, rg+16}; i=2,3 -> glimpse 1
    float s0[8], s1[8];
    #pragma unroll
    for (int j = 0; j < 8; j++) {
        s0[j] = celu_f(acc[0][j]) + celu_f(acc[1][j]);
        s1[j] = celu_f(acc[2][j]) + celu_f(acc[3][j]);
    }
    __syncthreads();   // all xs reads done before reuse as red
    *(float4*)&red[rg*132 + ch0]          = make_float4(s0[0], s0[1], s0[2], s0[3]);
    *(float4*)&red[rg*132 + ch0 + 4]      = make_float4(s0[4], s0[5], s0[6], s0[7]);
    *(float4*)&red[(16+rg)*132 + ch0]     = make_float4(s1[0], s1[1], s1[2], s1[3]);
    *(float4*)&red[(16+rg)*132 + ch0 + 4] = make_float4(s1[4], s1[5], s1[6], s1[7]);
    __syncthreads();
    {   // reduce 16 partials per (glimpse, ch); /32 for the mean
        const int gl = t >> 7, ch = t & 127;
        float a = 0.f;
        #pragma unroll
        for (int r2 = 0; r2 < 16; r2++) a += red[(gl*16 + r2)*132 + ch];
        agg[gl*128 + ch] = a * (1.f/32.f);
    }
    __syncthreads();

    // global conv: agg[128] @ W3g[128,256] + b3g -> celu -> f3 (both glimpses share w)
    {
        float a0 = b3g[t], a1 = a0;
        for (int k = 0; k < 128; k += 4) {
            const float4 ga = *(const float4*)&agg[k];
            const float4 gb = *(const float4*)&agg[128 + k];
            const float w0 = W3g[(k+0)*256+t], w1 = W3g[(k+1)*256+t];
            const float w2 = W3g[(k+2)*256+t], w3 = W3g[(k+3)*256+t];
            a0 += ga.x*w0 + ga.y*w1 + ga.z*w2 + ga.w*w3;
            a1 += gb.x*w0 + gb.y*w1 + gb.z*w2 + gb.w*w3;
        }
        f3s[t]       = celu_f(a0);
        f3s[256 + t] = celu_f(a1);
    }
    __syncthreads();

    // linear head: f3[256] @ Wlin[256,256] + blin
    {
        float a0 = blin[t], a1 = a0;
        for (int k = 0; k < 256; k += 4) {
            const float4 fa = *(const float4*)&f3s[k];
            const float4 fb = *(const float4*)&f3s[256 + k];
            const float w0 = Wlin[(k+0)*256+t], w1 = Wlin[(k+1)*256+t];
            const float w2 = Wlin[(k+2)*256+t], w3 = Wlin[(k+3)*256+t];
            a0 += fa.x*w0 + fa.y*w1 + fa.z*w2 + fa.w*w3;
            a1 += fb.x*w0 + fb.y*w1 + fb.z*w2 + fb.w*w3;
        }
        outs[t]       = a0;
        outs[256 + t] = a1;
    }
    out[OFF_F + (size_t)g0*256 + t]     = f3s[t];
    out[OFF_F + (size_t)(g0+1)*256 + t] = f3s[256 + t];
    __syncthreads();

    if (t < 128) {
        #pragma unroll
        for (int gl = 0; gl < 2; gl++) {
            const int g = g0 + gl;
            const float mu    = outs[gl*256 + t];
            const float sigma = softplus_f(outs[gl*256 + 128 + t]);
            const float z     = mu + sigma * eps[g*128 + t];
            out[OFF_MU + g*128 + t] = mu;
            out[OFF_SG + g*128 + t] = sigma;
            if (t < 64) out[OFF_ZW + g*64 + t] = z;
            else        out[OFF_ZM + g*64 + (t - 64)] = z;
        }
    }
}

extern "C" void kernel_launch(void* const* d_in, const int* in_sizes, int n_in,
                              void* d_out, int out_size, void* d_ws, size_t ws_size,
                              hipStream_t stream)
{
    const float* rgb  = (const float*)d_in[0];
    const float* pos  = (const float*)d_in[1];
    const float* pos1 = (const float*)d_in[2];
    const float* pos2 = (const float*)d_in[3];
    const int*   idx0 = (const int*)d_in[4];
    const int*   idx1 = (const int*)d_in[5];
    // d_in[6] (out_index2) is implicit: e // 32
    const float* eps  = (const float*)d_in[7];
    const float* W1l = (const float*)d_in[8],  *b1l = (const float*)d_in[9];
    const float* W1g = (const float*)d_in[10], *b1g = (const float*)d_in[11];
    const float* W2l = (const float*)d_in[12], *b2l = (const float*)d_in[13];
    const float* W2g = (const float*)d_in[14], *b2g = (const float*)d_in[15];
    const float* W3l = (const float*)d_in[16], *b3l = (const float*)d_in[17];
    const float* W3g = (const float*)d_in[18], *b3g = (const float*)d_in[19];
    const float* Wlin = (const float*)d_in[20], *blin = (const float*)d_in[21];

    float* f1 = (float*)d_ws;                 // M1*32 floats
    float* f2 = f1 + (size_t)M1_*32;          // M2*128 floats
    float* outp = (float*)d_out;

    k_conv1<<<G_,   256, 0, stream>>>(rgb, pos, pos1, idx0, W1l, b1l, W1g, b1g, f1);
    k_conv2<<<G_,   256, 0, stream>>>(f1, pos1, pos2, idx1, W2l, b2l, W2g, b2g, f2);
    k_conv3<<<G_/2, 256, 0, stream>>>(f2, pos2, W3l, b3l, W3g, b3g, Wlin, blin, eps, outp);
}

// Round 3
// 384.977 us; speedup vs baseline: 1.4197x; 1.4197x over previous
//
#include <hip/hip_runtime.h>
#include <cstddef>

#define G_   2048
#define NPG_ 512
#define CPG_ 128
#define CPG2_ 32
#define N0_  (G_*NPG_)
#define M1_  (G_*CPG_)
#define M2_  (G_*CPG2_)

// output layout (floats): z_what[G,64] | z_mask[G,64] | mu[G,128] | sigma[G,128] | f[G,256]
#define OFF_ZW 0
#define OFF_ZM (G_*64)
#define OFF_MU (2*G_*64)
#define OFF_SG (2*G_*64 + G_*128)
#define OFF_F  (2*G_*64 + 2*G_*128)

__device__ __forceinline__ float celu_f(float x)     { return x > 0.f ? x : __expf(x) - 1.f; }
__device__ __forceinline__ float softplus_f(float x) { return fmaxf(x, 0.f) + __logf(1.f + __expf(-fabsf(x))); }

// component select from float4 (dk is a compile-time constant after unroll)
__device__ __forceinline__ float f4c(const float4& v, int dk) {
    return dk == 0 ? v.x : dk == 1 ? v.y : dk == 2 ? v.z : v.w;
}

// ---------------- conv1: [N0 edges] -> f1 [M1,32], one block per glimpse ----------------
__global__ __launch_bounds__(256, 4) void k_conv1(
    const float* __restrict__ rgb, const float* __restrict__ pos, const float* __restrict__ pos1,
    const int* __restrict__ idx0, const float* __restrict__ W1l, const float* __restrict__ b1l,
    const float* __restrict__ W1g, const float* __restrict__ b1g, float* __restrict__ f1)
{
    const int g = blockIdx.x, t = threadIdx.x;
    __shared__ float agg[16*CPG_];    // [j*128 + lc]: atomic bank = lc&31 (random -> ~2-way, free)
    __shared__ float aggT[CPG_*20];   // [lc*20 + j], for b128 reads in global conv
    __shared__ float cnt[CPG_];
    __shared__ float sW1g[512];

    for (int i = t; i < 16*CPG_; i += 256) agg[i] = 0.f;
    if (t < CPG_) cnt[t] = 0.f;
    for (int i = t; i < 512; i += 256) sW1g[i] = W1g[i];

    float wj[16], wx[16], wy[16], wz[16], bb[16];
    #pragma unroll
    for (int j = 0; j < 16; j++) {
        wj[j] = W1l[j]; wx[j] = W1l[16+j]; wy[j] = W1l[32+j]; wz[j] = W1l[48+j]; bb[j] = b1l[j];
    }
    __syncthreads();

    #pragma unroll
    for (int r = 0; r < 2; r++) {
        const int p  = g*NPG_ + r*256 + t;
        const float x0 = rgb[p];
        const int c  = idx0[p];
        const int lc = c - g*CPG_;
        const float rx = pos[p*3+0] - pos1[c*3+0];
        const float ry = pos[p*3+1] - pos1[c*3+1];
        const float rz = pos[p*3+2] - pos1[c*3+2];
        #pragma unroll
        for (int j = 0; j < 16; j++) {
            const float h = bb[j] + x0*wj[j] + rx*wx[j] + ry*wy[j] + rz*wz[j];
            atomicAdd(&agg[j*CPG_ + lc], celu_f(h));
        }
        atomicAdd(&cnt[lc], 1.f);
    }
    __syncthreads();

    #pragma unroll
    for (int ii = 0; ii < 8; ii++) {
        const int idx = t + 256*ii;
        const int lc = idx & 127, j = idx >> 7;
        aggT[lc*20 + j] = agg[j*CPG_ + lc] / fmaxf(cnt[lc], 1.f);
    }
    __syncthreads();

    // global conv: [128,16] @ [16,32] -> celu -> f1
    const int oc = t & 31;
    float wreg[16];
    #pragma unroll
    for (int j = 0; j < 16; j++) wreg[j] = sW1g[j*32 + oc];
    const float bg = b1g[oc];
    #pragma unroll
    for (int i = 0; i < 16; i++) {
        const int lc = (t >> 5) + i*8;
        float a = bg;
        #pragma unroll
        for (int j = 0; j < 16; j += 4) {
            const float4 a4 = *(const float4*)&aggT[lc*20 + j];
            a += a4.x*wreg[j] + a4.y*wreg[j+1] + a4.z*wreg[j+2] + a4.w*wreg[j+3];
        }
        f1[(size_t)(g*CPG_ + lc)*32 + oc] = celu_f(a);
    }
}

// ---------------- conv2: [M1 edges] -> f2 [M2,128], one block per glimpse ----------------
// de-spilled: preload x-tile per k-quad (16 regs), stream weights 8 regs at a time
__global__ __launch_bounds__(256, 3) void k_conv2(
    const float* __restrict__ f1, const float* __restrict__ pos1, const float* __restrict__ pos2,
    const int* __restrict__ idx1, const float* __restrict__ W2l, const float* __restrict__ b2l,
    const float* __restrict__ W2g, const float* __restrict__ b2g, float* __restrict__ f2)
{
    const int g = blockIdx.x, t = threadIdx.x;
    __shared__ float sW2l[35*64];
    __shared__ float xs[CPG_*36];     // 35 inputs + pad
    __shared__ int   slc[CPG_];
    __shared__ float aggt[64*33];     // atomic target: [ch*33 + slc]
    __shared__ float aggr[32*68];     // [r*68 + ch] for b128 reads in global conv
    __shared__ float cnt[CPG2_];

    for (int i = t; i < 2240; i += 256) sW2l[i] = W2l[i];
    for (int i = t; i < 64*33; i += 256) aggt[i] = 0.f;
    if (t < CPG2_) cnt[t] = 0.f;
    {
        const int row = t >> 1, col = (t & 1) * 16;
        #pragma unroll
        for (int q = 0; q < 4; q++) {
            const float4 v = *(const float4*)&f1[(size_t)g*4096 + t*16 + q*4];
            *(float4*)&xs[row*36 + col + q*4] = v;
        }
    }
    if (t < CPG_) {
        const int c2 = idx1[g*CPG_ + t];
        slc[t] = c2 - g*CPG2_;
        #pragma unroll
        for (int d = 0; d < 3; d++)
            xs[t*36 + 32 + d] = pos1[(g*CPG_ + t)*3 + d] - pos2[c2*3 + d];
        xs[t*36 + 35] = 0.f;
    }
    __syncthreads();

    // local conv: thread tile = edges {eg+32i} x ch [8cg, 8cg+8)
    const int cg = t & 7, eg = t >> 3;
    const int ch0 = cg * 8;
    float acc[4][8];
    {
        const float4 bA = *(const float4*)&b2l[ch0];
        const float4 bB = *(const float4*)&b2l[ch0+4];
        #pragma unroll
        for (int i = 0; i < 4; i++) {
            acc[i][0]=bA.x; acc[i][1]=bA.y; acc[i][2]=bA.z; acc[i][3]=bA.w;
            acc[i][4]=bB.x; acc[i][5]=bB.y; acc[i][6]=bB.z; acc[i][7]=bB.w;
        }
    }
    #pragma unroll 2
    for (int kq = 0; kq < 8; kq++) {
        const int k = kq*4;
        float4 xr[4];
        #pragma unroll
        for (int i = 0; i < 4; i++) xr[i] = *(const float4*)&xs[(eg + 32*i)*36 + k];
        #pragma unroll
        for (int dk = 0; dk < 4; dk++) {
            const float4 wA = *(const float4*)&sW2l[(k+dk)*64 + ch0];
            const float4 wB = *(const float4*)&sW2l[(k+dk)*64 + ch0 + 4];
            #pragma unroll
            for (int i = 0; i < 4; i++) {
                const float xv = f4c(xr[i], dk);
                acc[i][0] += xv*wA.x; acc[i][1] += xv*wA.y; acc[i][2] += xv*wA.z; acc[i][3] += xv*wA.w;
                acc[i][4] += xv*wB.x; acc[i][5] += xv*wB.y; acc[i][6] += xv*wB.z; acc[i][7] += xv*wB.w;
            }
        }
    }
    {   // tail k = 32..34
        float4 xr[4];
        #pragma unroll
        for (int i = 0; i < 4; i++) xr[i] = *(const float4*)&xs[(eg + 32*i)*36 + 32];
        #pragma unroll
        for (int dk = 0; dk < 3; dk++) {
            const float4 wA = *(const float4*)&sW2l[(32+dk)*64 + ch0];
            const float4 wB = *(const float4*)&sW2l[(32+dk)*64 + ch0 + 4];
            #pragma unroll
            for (int i = 0; i < 4; i++) {
                const float xv = f4c(xr[i], dk);
                acc[i][0] += xv*wA.x; acc[i][1] += xv*wA.y; acc[i][2] += xv*wA.z; acc[i][3] += xv*wA.w;
                acc[i][4] += xv*wB.x; acc[i][5] += xv*wB.y; acc[i][6] += xv*wB.z; acc[i][7] += xv*wB.w;
            }
        }
    }
    #pragma unroll
    for (int i = 0; i < 4; i++) {
        const int s = slc[eg + 32*i];
        #pragma unroll
        for (int j = 0; j < 8; j++)
            atomicAdd(&aggt[(ch0 + j)*33 + s], celu_f(acc[i][j]));
    }
    if (t < CPG_) atomicAdd(&cnt[slc[t]], 1.f);
    __syncthreads();

    #pragma unroll
    for (int ii = 0; ii < 8; ii++) {
        const int idx = t + 256*ii;
        const int r = idx >> 6, ch = idx & 63;
        aggr[r*68 + ch] = aggt[ch*33 + r] / fmaxf(cnt[r], 1.f);
    }
    __syncthreads();

    // global conv: [32,64] @ [64,128]; rows {rg+8i} x ch [4cg2, 4cg2+4); W2g streamed from global
    const int cg2 = t & 31, rg = t >> 5;
    const int co = cg2 * 4;
    float acc2[4][4];
    {
        const float4 b4 = *(const float4*)&b2g[co];
        #pragma unroll
        for (int i = 0; i < 4; i++) { acc2[i][0]=b4.x; acc2[i][1]=b4.y; acc2[i][2]=b4.z; acc2[i][3]=b4.w; }
    }
    #pragma unroll 2
    for (int kq = 0; kq < 16; kq++) {
        const int k = kq*4;
        float4 xr[4];
        #pragma unroll
        for (int i = 0; i < 4; i++) xr[i] = *(const float4*)&aggr[(rg + 8*i)*68 + k];
        #pragma unroll
        for (int dk = 0; dk < 4; dk++) {
            const float4 w4 = *(const float4*)&W2g[(k+dk)*128 + co];
            #pragma unroll
            for (int i = 0; i < 4; i++) {
                const float xv = f4c(xr[i], dk);
                acc2[i][0] += xv*w4.x; acc2[i][1] += xv*w4.y; acc2[i][2] += xv*w4.z; acc2[i][3] += xv*w4.w;
            }
        }
    }
    #pragma unroll
    for (int i = 0; i < 4; i++) {
        const int r = rg + 8*i;
        float4 o;
        o.x = celu_f(acc2[i][0]); o.y = celu_f(acc2[i][1]);
        o.z = celu_f(acc2[i][2]); o.w = celu_f(acc2[i][3]);
        *(float4*)&f2[(size_t)(g*CPG2_ + r)*128 + co] = o;
    }
}

// ---------------- conv3 + linear + sample: 2 glimpses per block ----------------
__global__ __launch_bounds__(256, 4) void k_conv3(
    const float* __restrict__ f2, const float* __restrict__ pos2,
    const float* __restrict__ W3l, const float* __restrict__ b3l,
    const float* __restrict__ W3g, const float* __restrict__ b3g,
    const float* __restrict__ Wlin, const float* __restrict__ blin,
    const float* __restrict__ eps, float* __restrict__ out)
{
    const int g0 = blockIdx.x * 2, t = threadIdx.x;
    __shared__ float xs[64*132];   // 2 glimpses x 32 rows x (128 feat + 3 pos + pad); reused as red
    __shared__ float agg[256];
    __shared__ float f3s[512];
    __shared__ float outs[512];
    float* const red = xs;

    {
        const int row = t >> 2, col = (t & 3) * 32;
        #pragma unroll
        for (int q = 0; q < 8; q++) {
            const float4 v = *(const float4*)&f2[(size_t)g0*4096 + t*32 + q*4];
            *(float4*)&xs[row*132 + col + q*4] = v;
        }
    }
    if (t < 64) {
        #pragma unroll
        for (int d = 0; d < 3; d++)
            xs[t*132 + 128 + d] = pos2[(g0*CPG2_ + t)*3 + d];
        xs[t*132 + 131] = 0.f;
    }
    __syncthreads();

    // local conv: rows {rg+16i} x ch [8cg, 8cg+8); x-tile preloaded per kq, W3l streamed (global/L2)
    const int cg = t & 15, rg = t >> 4;
    const int ch0 = cg * 8;
    float acc[4][8];
    {
        const float4 bA = *(const float4*)&b3l[ch0];
        const float4 bB = *(const float4*)&b3l[ch0+4];
        #pragma unroll
        for (int i = 0; i < 4; i++) {
            acc[i][0]=bA.x; acc[i][1]=bA.y; acc[i][2]=bA.z; acc[i][3]=bA.w;
            acc[i][4]=bB.x; acc[i][5]=bB.y; acc[i][6]=bB.z; acc[i][7]=bB.w;
        }
    }
    #pragma unroll 2
    for (int kq = 0; kq < 32; kq++) {
        const int k = kq*4;
        float4 xr[4];
        #pragma unroll
        for (int i = 0; i < 4; i++) xr[i] = *(const float4*)&xs[(rg + 16*i)*132 + k];
        #pragma unroll
        for (int dk = 0; dk < 4; dk++) {
            const float4 wA = *(const float4*)&W3l[(k+dk)*128 + ch0];
            const float4 wB = *(const float4*)&W3l[(k+dk)*128 + ch0 + 4];
            #pragma unroll
            for (int i = 0; i < 4; i++) {
                const float xv = f4c(xr[i], dk);
                acc[i][0] += xv*wA.x; acc[i][1] += xv*wA.y; acc[i][2] += xv*wA.z; acc[i][3] += xv*wA.w;
                acc[i][4] += xv*wB.x; acc[i][5] += xv*wB.y; acc[i][6] += xv*wB.z; acc[i][7] += xv*wB.w;
            }
        }
    }
    {   // tail k = 128..130
        float4 xr[4];
        #pragma unroll
        for (int i = 0; i < 4; i++) xr[i] = *(const float4*)&xs[(rg + 16*i)*132 + 128];
        #pragma unroll
        for (int dk = 0; dk < 3; dk++) {
            const float4 wA = *(const float4*)&W3l[(128+dk)*128 + ch0];
            const float4 wB = *(const float4*)&W3l[(128+dk)*128 + ch0 + 4];
            #pragma unroll
            for (int i = 0; i < 4; i++) {
                const float xv = f4c(xr[i], dk);
                acc[i][0] += xv*wA.x; acc[i][1] += xv*wA.y; acc[i][2] += xv*wA.z; acc[i][3] += xv*wA.w;
                acc[i][4] += xv*wB.x; acc[i][5] += xv*wB.y; acc[i][6] += xv*wB.z; acc[i][7] += xv*wB.w;
            }
        }
    }
    float s0[8], s1[8];
    #pragma unroll
    for (int j = 0; j < 8; j++) {
        s0[j] = celu_f(acc[0][j]) + celu_f(acc[1][j]);
        s1[j] = celu_f(acc[2][j]) + celu_f(acc[3][j]);
    }
    __syncthreads();
    *(float4*)&red[rg*132 + ch0]          = make_float4(s0[0], s0[1], s0[2], s0[3]);
    *(float4*)&red[rg*132 + ch0 + 4]      = make_float4(s0[4], s0[5], s0[6], s0[7]);
    *(float4*)&red[(16+rg)*132 + ch0]     = make_float4(s1[0], s1[1], s1[2], s1[3]);
    *(float4*)&red[(16+rg)*132 + ch0 + 4] = make_float4(s1[4], s1[5], s1[6], s1[7]);
    __syncthreads();
    {
        const int gl = t >> 7, ch = t & 127;
        float a = 0.f;
        #pragma unroll
        for (int r2 = 0; r2 < 16; r2++) a += red[(gl*16 + r2)*132 + ch];
        agg[gl*128 + ch] = a * (1.f/32.f);
    }
    __syncthreads();

    // global conv: agg[128] @ W3g[128,256] + b3g -> celu -> f3
    {
        float a0 = b3g[t], a1 = a0;
        #pragma unroll 2
        for (int k = 0; k < 128; k += 4) {
            const float4 ga = *(const float4*)&agg[k];
            const float4 gb = *(const float4*)&agg[128 + k];
            const float w0 = W3g[(k+0)*256+t], w1 = W3g[(k+1)*256+t];
            const float w2 = W3g[(k+2)*256+t], w3 = W3g[(k+3)*256+t];
            a0 += ga.x*w0 + ga.y*w1 + ga.z*w2 + ga.w*w3;
            a1 += gb.x*w0 + gb.y*w1 + gb.z*w2 + gb.w*w3;
        }
        f3s[t]       = celu_f(a0);
        f3s[256 + t] = celu_f(a1);
    }
    __syncthreads();

    // linear head: f3[256] @ Wlin[256,256] + blin
    {
        float a0 = blin[t], a1 = a0;
        #pragma unroll 2
        for (int k = 0; k < 256; k += 4) {
            const float4 fa = *(const float4*)&f3s[k];
            const float4 fb = *(const float4*)&f3s[256 + k];
            const float w0 = Wlin[(k+0)*256+t], w1 = Wlin[(k+1)*256+t];
            const float w2 = Wlin[(k+2)*256+t], w3 = Wlin[(k+3)*256+t];
            a0 += fa.x*w0 + fa.y*w1 + fa.z*w2 + fa.w*w3;
            a1 += fb.x*w0 + fb.y*w1 + fb.z*w2 + fb.w*w3;
        }
        outs[t]       = a0;
        outs[256 + t] = a1;
    }
    out[OFF_F + (size_t)g0*256 + t]     = f3s[t];
    out[OFF_F + (size_t)(g0+1)*256 + t] = f3s[256 + t];
    __syncthreads();

    if (t < 128) {
        #pragma unroll
        for (int gl = 0; gl < 2; gl++) {
            const int g = g0 + gl;
            const float mu    = outs[gl*256 + t];
            const float sigma = softplus_f(outs[gl*256 + 128 + t]);
            const float z     = mu + sigma * eps[g*128 + t];
            out[OFF_MU + g*128 + t] = mu;
            out[OFF_SG + g*128 + t] = sigma;
            if (t < 64) out[OFF_ZW + g*64 + t] = z;
            else        out[OFF_ZM + g*64 + (t - 64)] = z;
        }
    }
}

extern "C" void kernel_launch(void* const* d_in, const int* in_sizes, int n_in,
                              void* d_out, int out_size, void* d_ws, size_t ws_size,
                              hipStream_t stream)
{
    const float* rgb  = (const float*)d_in[0];
    const float* pos  = (const float*)d_in[1];
    const float* pos1 = (const float*)d_in[2];
    const float* pos2 = (const float*)d_in[3];
    const int*   idx0 = (const int*)d_in[4];
    const int*   idx1 = (const int*)d_in[5];
    const float* eps  = (const float*)d_in[7];
    const float* W1l = (const float*)d_in[8],  *b1l = (const float*)d_in[9];
    const float* W1g = (const float*)d_in[10], *b1g = (const float*)d_in[11];
    const float* W2l = (const float*)d_in[12], *b2l = (const float*)d_in[13];
    const float* W2g = (const float*)d_in[14], *b2g = (const float*)d_in[15];
    const float* W3l = (const float*)d_in[16], *b3l = (const float*)d_in[17];
    const float* W3g = (const float*)d_in[18], *b3g = (const float*)d_in[19];
    const float* Wlin = (const float*)d_in[20], *blin = (const float*)d_in[21];

    float* f1 = (float*)d_ws;
    float* f2 = f1 + (size_t)M1_*32;
    float* outp = (float*)d_out;

    k_conv1<<<G_,   256, 0, stream>>>(rgb, pos, pos1, idx0, W1l, b1l, W1g, b1g, f1);
    k_conv2<<<G_,   256, 0, stream>>>(f1, pos1, pos2, idx1, W2l, b2l, W2g, b2g, f2);
    k_conv3<<<G_/2, 256, 0, stream>>>(f2, pos2, W3l, b3l, W3g, b3g, Wlin, blin, eps, outp);
}

// Round 5
// 371.018 us; speedup vs baseline: 1.4731x; 1.0376x over previous
//
#include <hip/hip_runtime.h>
#include <hip/hip_bf16.h>
#include <cstddef>

#define G_   2048
#define NPG_ 512
#define CPG_ 128
#define CPG2_ 32
#define N0_  (G_*NPG_)
#define M1_  (G_*CPG_)
#define M2_  (G_*CPG2_)

// output layout (floats): z_what[G,64] | z_mask[G,64] | mu[G,128] | sigma[G,128] | f[G,256]
#define OFF_ZW 0
#define OFF_ZM (G_*64)
#define OFF_MU (2*G_*64)
#define OFF_SG (2*G_*64 + G_*128)
#define OFF_F  (2*G_*64 + 2*G_*128)

__device__ __forceinline__ float celu_f(float x)     { return x > 0.f ? x : __expf(x) - 1.f; }
__device__ __forceinline__ float softplus_f(float x) { return fmaxf(x, 0.f) + __logf(1.f + __expf(-fabsf(x))); }

__device__ __forceinline__ float f4c(const float4& v, int dk) {
    return dk == 0 ? v.x : dk == 1 ? v.y : dk == 2 ? v.z : v.w;
}
// bf16 pair-in-uint2 extract: dk compile-time after unroll -> 1 instr
__device__ __forceinline__ float bfsel(const uint2& u, int dk) {
    const unsigned w = (dk < 2) ? u.x : u.y;
    const unsigned b = (dk & 1) ? (w & 0xffff0000u) : (w << 16);
    return __uint_as_float(b);
}
__device__ __forceinline__ unsigned short f2bf(float x) {
    __hip_bfloat16 h = __float2bfloat16(x);
    return *reinterpret_cast<unsigned short*>(&h);
}

// ---------------- conv1: [N0 edges] -> f1 [M1,32] bf16, one block per glimpse ----------------
__global__ __launch_bounds__(256, 4) void k_conv1(
    const float* __restrict__ rgb, const float* __restrict__ pos, const float* __restrict__ pos1,
    const int* __restrict__ idx0, const float* __restrict__ W1l, const float* __restrict__ b1l,
    const float* __restrict__ W1g, const float* __restrict__ b1g, unsigned short* __restrict__ f1)
{
    const int g = blockIdx.x, t = threadIdx.x;
    __shared__ float agg[16*CPG_];    // [j*128 + lc]: atomic bank = lc&31 (random -> ~2-way, free)
    __shared__ float aggT[CPG_*20];   // [lc*20 + j], b128 reads in global conv
    __shared__ float cnt[CPG_];
    __shared__ float sW1g[512];

    for (int i = t; i < 16*CPG_; i += 256) agg[i] = 0.f;
    if (t < CPG_) cnt[t] = 0.f;
    for (int i = t; i < 512; i += 256) sW1g[i] = W1g[i];

    float wj[16], wx[16], wy[16], wz[16], bb[16];
    #pragma unroll
    for (int j = 0; j < 16; j++) {
        wj[j] = W1l[j]; wx[j] = W1l[16+j]; wy[j] = W1l[32+j]; wz[j] = W1l[48+j]; bb[j] = b1l[j];
    }
    __syncthreads();

    #pragma unroll
    for (int r = 0; r < 2; r++) {
        const int p  = g*NPG_ + r*256 + t;
        const float x0 = rgb[p];
        const int c  = idx0[p];
        const int lc = c - g*CPG_;
        const float rx = pos[p*3+0] - pos1[c*3+0];
        const float ry = pos[p*3+1] - pos1[c*3+1];
        const float rz = pos[p*3+2] - pos1[c*3+2];
        #pragma unroll
        for (int j = 0; j < 16; j++) {
            const float h = bb[j] + x0*wj[j] + rx*wx[j] + ry*wy[j] + rz*wz[j];
            atomicAdd(&agg[j*CPG_ + lc], celu_f(h));
        }
        atomicAdd(&cnt[lc], 1.f);
    }
    __syncthreads();

    #pragma unroll
    for (int ii = 0; ii < 8; ii++) {
        const int idx = t + 256*ii;
        const int lc = idx & 127, j = idx >> 7;
        aggT[lc*20 + j] = agg[j*CPG_ + lc] / fmaxf(cnt[lc], 1.f);
    }
    __syncthreads();

    // global conv: [128,16] @ [16,32] -> celu -> f1 (bf16)
    const int oc = t & 31;
    float wreg[16];
    #pragma unroll
    for (int j = 0; j < 16; j++) wreg[j] = sW1g[j*32 + oc];
    const float bg = b1g[oc];
    #pragma unroll
    for (int i = 0; i < 16; i++) {
        const int lc = (t >> 5) + i*8;
        float a = bg;
        #pragma unroll
        for (int j = 0; j < 16; j += 4) {
            const float4 a4 = *(const float4*)&aggT[lc*20 + j];
            a += a4.x*wreg[j] + a4.y*wreg[j+1] + a4.z*wreg[j+2] + a4.w*wreg[j+3];
        }
        f1[(size_t)(g*CPG_ + lc)*32 + oc] = f2bf(celu_f(a));
    }
}

// ---------------- conv2: f1(bf16) -> f2 [M2,128] bf16, one block per glimpse ----------------
__global__ __launch_bounds__(256, 5) void k_conv2(
    const unsigned short* __restrict__ f1, const float* __restrict__ pos1, const float* __restrict__ pos2,
    const int* __restrict__ idx1, const float* __restrict__ W2l, const float* __restrict__ b2l,
    const float* __restrict__ W2g, const float* __restrict__ b2g, unsigned short* __restrict__ f2)
{
    const int g = blockIdx.x, t = threadIdx.x;
    __shared__ __align__(16) unsigned short xs16[CPG_*40];  // 35 bf16 inputs + pad; stride 40 -> 2-way banks
    __shared__ float sW2l[35*64];
    __shared__ int   slc[CPG_];
    __shared__ float aggt[64*33];     // atomic target [ch*33 + slc]
    __shared__ float cnt[CPG2_];
    float* const aggr = (float*)xs16; // overlay: [r*68 + ch] (2176 floats = 8704 B <= 10240 B), live after xs dead

    for (int i = t; i < 2240; i += 256) sW2l[i] = W2l[i];
    for (int i = t; i < 64*33; i += 256) aggt[i] = 0.f;
    if (t < CPG2_) cnt[t] = 0.f;
    {   // f1 glimpse tile: 4096 bf16 = 512 uint4; 2 uint4 (16 bf16) per thread
        const uint4 v0 = ((const uint4*)f1)[(size_t)g*512 + t*2];
        const uint4 v1 = ((const uint4*)f1)[(size_t)g*512 + t*2 + 1];
        const int row = t >> 1, col = (t & 1) * 16;   // elements 16t..16t+15: row=16t/32, col=16t%32
        *(uint4*)&xs16[row*40 + col]     = v0;
        *(uint4*)&xs16[row*40 + col + 8] = v1;
    }
    if (t < CPG_) {
        const int c2 = idx1[g*CPG_ + t];
        slc[t] = c2 - g*CPG2_;
        #pragma unroll
        for (int d = 0; d < 3; d++)
            xs16[t*40 + 32 + d] = f2bf(pos1[(g*CPG_ + t)*3 + d] - pos2[c2*3 + d]);
        xs16[t*40 + 35] = 0;
    }
    __syncthreads();

    // local conv: edges {eg+32i} x ch [8cg, 8cg+8)
    const int cg = t & 7, eg = t >> 3;
    const int ch0 = cg * 8;
    float acc[4][8];
    {
        const float4 bA = *(const float4*)&b2l[ch0];
        const float4 bB = *(const float4*)&b2l[ch0+4];
        #pragma unroll
        for (int i = 0; i < 4; i++) {
            acc[i][0]=bA.x; acc[i][1]=bA.y; acc[i][2]=bA.z; acc[i][3]=bA.w;
            acc[i][4]=bB.x; acc[i][5]=bB.y; acc[i][6]=bB.z; acc[i][7]=bB.w;
        }
    }
    #pragma unroll 2
    for (int kq = 0; kq < 8; kq++) {
        const int k = kq*4;
        uint2 xr[4];
        #pragma unroll
        for (int i = 0; i < 4; i++) xr[i] = *(const uint2*)&xs16[(eg + 32*i)*40 + k];
        #pragma unroll
        for (int dk = 0; dk < 4; dk++) {
            const float4 wA = *(const float4*)&sW2l[(k+dk)*64 + ch0];
            const float4 wB = *(const float4*)&sW2l[(k+dk)*64 + ch0 + 4];
            #pragma unroll
            for (int i = 0; i < 4; i++) {
                const float xv = bfsel(xr[i], dk);
                acc[i][0] += xv*wA.x; acc[i][1] += xv*wA.y; acc[i][2] += xv*wA.z; acc[i][3] += xv*wA.w;
                acc[i][4] += xv*wB.x; acc[i][5] += xv*wB.y; acc[i][6] += xv*wB.z; acc[i][7] += xv*wB.w;
            }
        }
    }
    {   // tail k = 32..34 (35 padded to 0)
        uint2 xr[4];
        #pragma unroll
        for (int i = 0; i < 4; i++) xr[i] = *(const uint2*)&xs16[(eg + 32*i)*40 + 32];
        #pragma unroll
        for (int dk = 0; dk < 3; dk++) {
            const float4 wA = *(const float4*)&sW2l[(32+dk)*64 + ch0];
            const float4 wB = *(const float4*)&sW2l[(32+dk)*64 + ch0 + 4];
            #pragma unroll
            for (int i = 0; i < 4; i++) {
                const float xv = bfsel(xr[i], dk);
                acc[i][0] += xv*wA.x; acc[i][1] += xv*wA.y; acc[i][2] += xv*wA.z; acc[i][3] += xv*wA.w;
                acc[i][4] += xv*wB.x; acc[i][5] += xv*wB.y; acc[i][6] += xv*wB.z; acc[i][7] += xv*wB.w;
            }
        }
    }
    #pragma unroll
    for (int i = 0; i < 4; i++) {
        const int s = slc[eg + 32*i];
        #pragma unroll
        for (int j = 0; j < 8; j++)
            atomicAdd(&aggt[(ch0 + j)*33 + s], celu_f(acc[i][j]));
    }
    if (t < CPG_) atomicAdd(&cnt[slc[t]], 1.f);
    __syncthreads();   // xs16 dead; aggr overlay becomes live

    #pragma unroll
    for (int ii = 0; ii < 8; ii++) {
        const int idx = t + 256*ii;
        const int r = idx >> 6, ch = idx & 63;
        aggr[r*68 + ch] = aggt[ch*33 + r] / fmaxf(cnt[r], 1.f);
    }
    __syncthreads();

    // global conv: [32,64] @ [64,128]; rows {rg+8i} x ch [4cg2, 4cg2+4); W2g streamed from global
    const int cg2 = t & 31, rg = t >> 5;
    const int co = cg2 * 4;
    float acc2[4][4];
    {
        const float4 b4 = *(const float4*)&b2g[co];
        #pragma unroll
        for (int i = 0; i < 4; i++) { acc2[i][0]=b4.x; acc2[i][1]=b4.y; acc2[i][2]=b4.z; acc2[i][3]=b4.w; }
    }
    #pragma unroll 2
    for (int kq = 0; kq < 16; kq++) {
        const int k = kq*4;
        float4 xr[4];
        #pragma unroll
        for (int i = 0; i < 4; i++) xr[i] = *(const float4*)&aggr[(rg + 8*i)*68 + k];
        #pragma unroll
        for (int dk = 0; dk < 4; dk++) {
            const float4 w4 = *(const float4*)&W2g[(k+dk)*128 + co];
            #pragma unroll
            for (int i = 0; i < 4; i++) {
                const float xv = f4c(xr[i], dk);
                acc2[i][0] += xv*w4.x; acc2[i][1] += xv*w4.y; acc2[i][2] += xv*w4.z; acc2[i][3] += xv*w4.w;
            }
        }
    }
    #pragma unroll
    for (int i = 0; i < 4; i++) {
        const int r = rg + 8*i;
        const unsigned p0 = ((unsigned)f2bf(celu_f(acc2[i][1])) << 16) | f2bf(celu_f(acc2[i][0]));
        const unsigned p1 = ((unsigned)f2bf(celu_f(acc2[i][3])) << 16) | f2bf(celu_f(acc2[i][2]));
        *(uint2*)&f2[(size_t)(g*CPG2_ + r)*128 + co] = make_uint2(p0, p1);
    }
}

// ---------------- conv3 + linear + sample: 2 glimpses per block, f2 bf16 in ----------------
__global__ __launch_bounds__(256, 5) void k_conv3(
    const unsigned short* __restrict__ f2, const float* __restrict__ pos2,
    const float* __restrict__ W3l, const float* __restrict__ b3l,
    const float* __restrict__ W3g, const float* __restrict__ b3g,
    const float* __restrict__ Wlin, const float* __restrict__ blin,
    const float* __restrict__ eps, float* __restrict__ out)
{
    const int g0 = blockIdx.x * 2, t = threadIdx.x;
    __shared__ __align__(16) unsigned short xs16[64*136];  // 128 feat + 3 pos + pad; 2-way banks
    __shared__ float agg[256];
    __shared__ float f3s[512];
    __shared__ float outs[512];
    float* const red = (float*)xs16;   // overlay stride 132 (4224 floats = 16896 B <= 17408 B)

    {   // stage f2 tile: 8192 bf16 = 1024 uint4; 4 uint4 (32 bf16) per thread
        const int row = t >> 2, col = (t & 3) * 32;   // elements 32t..32t+31: row=32t/128, col=32t%128
        const size_t base = (size_t)g0*512 + t*4;
        const uint4 v0 = ((const uint4*)f2)[base + 0];
        const uint4 v1 = ((const uint4*)f2)[base + 1];
        const uint4 v2 = ((const uint4*)f2)[base + 2];
        const uint4 v3 = ((const uint4*)f2)[base + 3];
        *(uint4*)&xs16[row*136 + col]      = v0;
        *(uint4*)&xs16[row*136 + col + 8]  = v1;
        *(uint4*)&xs16[row*136 + col + 16] = v2;
        *(uint4*)&xs16[row*136 + col + 24] = v3;
    }
    if (t < 64) {
        #pragma unroll
        for (int d = 0; d < 3; d++)
            xs16[t*136 + 128 + d] = f2bf(pos2[(g0*CPG2_ + t)*3 + d]);
        xs16[t*136 + 131] = 0;
    }
    __syncthreads();

    // local conv: rows {rg+16i} x ch [8cg, 8cg+8); W3l streamed (L2)
    const int cg = t & 15, rg = t >> 4;
    const int ch0 = cg * 8;
    float acc[4][8];
    {
        const float4 bA = *(const float4*)&b3l[ch0];
        const float4 bB = *(const float4*)&b3l[ch0+4];
        #pragma unroll
        for (int i = 0; i < 4; i++) {
            acc[i][0]=bA.x; acc[i][1]=bA.y; acc[i][2]=bA.z; acc[i][3]=bA.w;
            acc[i][4]=bB.x; acc[i][5]=bB.y; acc[i][6]=bB.z; acc[i][7]=bB.w;
        }
    }
    #pragma unroll 2
    for (int kq = 0; kq < 32; kq++) {
        const int k = kq*4;
        uint2 xr[4];
        #pragma unroll
        for (int i = 0; i < 4; i++) xr[i] = *(const uint2*)&xs16[(rg + 16*i)*136 + k];
        #pragma unroll
        for (int dk = 0; dk < 4; dk++) {
            const float4 wA = *(const float4*)&W3l[(k+dk)*128 + ch0];
            const float4 wB = *(const float4*)&W3l[(k+dk)*128 + ch0 + 4];
            #pragma unroll
            for (int i = 0; i < 4; i++) {
                const float xv = bfsel(xr[i], dk);
                acc[i][0] += xv*wA.x; acc[i][1] += xv*wA.y; acc[i][2] += xv*wA.z; acc[i][3] += xv*wA.w;
                acc[i][4] += xv*wB.x; acc[i][5] += xv*wB.y; acc[i][6] += xv*wB.z; acc[i][7] += xv*wB.w;
            }
        }
    }
    {   // tail k = 128..130 (131 padded to 0)
        uint2 xr[4];
        #pragma unroll
        for (int i = 0; i < 4; i++) xr[i] = *(const uint2*)&xs16[(rg + 16*i)*136 + 128];
        #pragma unroll
        for (int dk = 0; dk < 3; dk++) {
            const float4 wA = *(const float4*)&W3l[(128+dk)*128 + ch0];
            const float4 wB = *(const float4*)&W3l[(128+dk)*128 + ch0 + 4];
            #pragma unroll
            for (int i = 0; i < 4; i++) {
                const float xv = bfsel(xr[i], dk);
                acc[i][0] += xv*wA.x; acc[i][1] += xv*wA.y; acc[i][2] += xv*wA.z; acc[i][3] += xv*wA.w;
                acc[i][4] += xv*wB.x; acc[i][5] += xv*wB.y; acc[i][6] += xv*wB.z; acc[i][7] += xv*wB.w;
            }
        }
    }
    float s0[8], s1[8];
    #pragma unroll
    for (int j = 0; j < 8; j++) {
        s0[j] = celu_f(acc[0][j]) + celu_f(acc[1][j]);
        s1[j] = celu_f(acc[2][j]) + celu_f(acc[3][j]);
    }
    __syncthreads();   // xs16 dead; red overlay becomes live
    *(float4*)&red[rg*132 + ch0]          = make_float4(s0[0], s0[1], s0[2], s0[3]);
    *(float4*)&red[rg*132 + ch0 + 4]      = make_float4(s0[4], s0[5], s0[6], s0[7]);
    *(float4*)&red[(16+rg)*132 + ch0]     = make_float4(s1[0], s1[1], s1[2], s1[3]);
    *(float4*)&red[(16+rg)*132 + ch0 + 4] = make_float4(s1[4], s1[5], s1[6], s1[7]);
    __syncthreads();
    {
        const int gl = t >> 7, ch = t & 127;
        float a = 0.f;
        #pragma unroll
        for (int r2 = 0; r2 < 16; r2++) a += red[(gl*16 + r2)*132 + ch];
        agg[gl*128 + ch] = a * (1.f/32.f);
    }
    __syncthreads();

    // global conv: agg[128] @ W3g[128,256] + b3g -> celu -> f3
    {
        float a0 = b3g[t], a1 = a0;
        #pragma unroll 2
        for (int k = 0; k < 128; k += 4) {
            const float4 ga = *(const float4*)&agg[k];
            const float4 gb = *(const float4*)&agg[128 + k];
            const float w0 = W3g[(k+0)*256+t], w1 = W3g[(k+1)*256+t];
            const float w2 = W3g[(k+2)*256+t], w3 = W3g[(k+3)*256+t];
            a0 += ga.x*w0 + ga.y*w1 + ga.z*w2 + ga.w*w3;
            a1 += gb.x*w0 + gb.y*w1 + gb.z*w2 + gb.w*w3;
        }
        f3s[t]       = celu_f(a0);
        f3s[256 + t] = celu_f(a1);
    }
    __syncthreads();

    // linear head: f3[256] @ Wlin[256,256] + blin
    {
        float a0 = blin[t], a1 = a0;
        #pragma unroll 2
        for (int k = 0; k < 256; k += 4) {
            const float4 fa = *(const float4*)&f3s[k];
            const float4 fb = *(const float4*)&f3s[256 + k];
            const float w0 = Wlin[(k+0)*256+t], w1 = Wlin[(k+1)*256+t];
            const float w2 = Wlin[(k+2)*256+t], w3 = Wlin[(k+3)*256+t];
            a0 += fa.x*w0 + fa.y*w1 + fa.z*w2 + fa.w*w3;
            a1 += fb.x*w0 + fb.y*w1 + fb.z*w2 + fb.w*w3;
        }
        outs[t]       = a0;
        outs[256 + t] = a1;
    }
    out[OFF_F + (size_t)g0*256 + t]     = f3s[t];
    out[OFF_F + (size_t)(g0+1)*256 + t] = f3s[256 + t];
    __syncthreads();

    if (t < 128) {
        #pragma unroll
        for (int gl = 0; gl < 2; gl++) {
            const int g = g0 + gl;
            const float mu    = outs[gl*256 + t];
            const float sigma = softplus_f(outs[gl*256 + 128 + t]);
            const float z     = mu + sigma * eps[g*128 + t];
            out[OFF_MU + g*128 + t] = mu;
            out[OFF_SG + g*128 + t] = sigma;
            if (t < 64) out[OFF_ZW + g*64 + t] = z;
            else        out[OFF_ZM + g*64 + (t - 64)] = z;
        }
    }
}

extern "C" void kernel_launch(void* const* d_in, const int* in_sizes, int n_in,
                              void* d_out, int out_size, void* d_ws, size_t ws_size,
                              hipStream_t stream)
{
    const float* rgb  = (const float*)d_in[0];
    const float* pos  = (const float*)d_in[1];
    const float* pos1 = (const float*)d_in[2];
    const float* pos2 = (const float*)d_in[3];
    const int*   idx0 = (const int*)d_in[4];
    const int*   idx1 = (const int*)d_in[5];
    const float* eps  = (const float*)d_in[7];
    const float* W1l = (const float*)d_in[8],  *b1l = (const float*)d_in[9];
    const float* W1g = (const float*)d_in[10], *b1g = (const float*)d_in[11];
    const float* W2l = (const float*)d_in[12], *b2l = (const float*)d_in[13];
    const float* W2g = (const float*)d_in[14], *b2g = (const float*)d_in[15];
    const float* W3l = (const float*)d_in[16], *b3l = (const float*)d_in[17];
    const float* W3g = (const float*)d_in[18], *b3g = (const float*)d_in[19];
    const float* Wlin = (const float*)d_in[20], *blin = (const float*)d_in[21];

    unsigned short* f1 = (unsigned short*)d_ws;          // M1*32 bf16 = 16.8 MB
    unsigned short* f2 = f1 + (size_t)M1_*32;            // M2*128 bf16 = 16.8 MB
    float* outp = (float*)d_out;

    k_conv1<<<G_,   256, 0, stream>>>(rgb, pos, pos1, idx0, W1l, b1l, W1g, b1g, f1);
    k_conv2<<<G_,   256, 0, stream>>>(f1, pos1, pos2, idx1, W2l, b2l, W2g, b2g, f2);
    k_conv3<<<G_/2, 256, 0, stream>>>(f2, pos2, W3l, b3l, W3g, b3g, Wlin, blin, eps, outp);
}

// Round 6
// 295.008 us; speedup vs baseline: 1.8526x; 1.2577x over previous
//
#include <hip/hip_runtime.h>
#include <hip/hip_bf16.h>
#include <cstddef>

#define G_   2048
#define NPG_ 512
#define CPG_ 128
#define CPG2_ 32
#define N0_  (G_*NPG_)
#define M1_  (G_*CPG_)
#define M2_  (G_*CPG2_)

// output layout (floats): z_what[G,64] | z_mask[G,64] | mu[G,128] | sigma[G,128] | f[G,256]
#define OFF_ZW 0
#define OFF_ZM (G_*64)
#define OFF_MU (2*G_*64)
#define OFF_SG (2*G_*64 + G_*128)
#define OFF_F  (2*G_*64 + 2*G_*128)

__device__ __forceinline__ float celu_f(float x)     { return x > 0.f ? x : __expf(x) - 1.f; }
__device__ __forceinline__ float softplus_f(float x) { return fmaxf(x, 0.f) + __logf(1.f + __expf(-fabsf(x))); }

__device__ __forceinline__ float f4c(const float4& v, int dk) {
    return dk == 0 ? v.x : dk == 1 ? v.y : dk == 2 ? v.z : v.w;
}
// bf16 pair-in-uint2 extract: dk compile-time after unroll -> 1 instr
__device__ __forceinline__ float bfsel(const uint2& u, int dk) {
    const unsigned w = (dk < 2) ? u.x : u.y;
    const unsigned b = (dk & 1) ? (w & 0xffff0000u) : (w << 16);
    return __uint_as_float(b);
}
__device__ __forceinline__ unsigned short f2bf(float x) {
    __hip_bfloat16 h = __float2bfloat16(x);
    return *reinterpret_cast<unsigned short*>(&h);
}

// ---------------- conv1: counting-sort per glimpse, zero fp atomics ----------------
__global__ __launch_bounds__(256, 6) void k_conv1(
    const float* __restrict__ rgb, const float* __restrict__ pos, const float* __restrict__ pos1,
    const int* __restrict__ idx0, const float* __restrict__ W1l, const float* __restrict__ b1l,
    const float* __restrict__ W1g, const float* __restrict__ b1g, unsigned short* __restrict__ f1)
{
    const int g = blockIdx.x, t = threadIdx.x;
    __shared__ float sx0[NPG_], srx[NPG_], sry[NPG_], srz[NPG_];   // SoA point data
    __shared__ unsigned short slc1[NPG_], order[NPG_];
    __shared__ int cnt[CPG_], start[CPG_], ctr[CPG_], scan[CPG_];
    __shared__ float aggT[CPG_*20];    // [lc*20 + j], b128-friendly for global conv
    __shared__ float sW1g[512];

    for (int i = t; i < 512; i += 256) sW1g[i] = W1g[i];
    if (t < CPG_) cnt[t] = 0;
    __syncthreads();

    // Phase A: stage point features + count cluster sizes (1 int atomic per point)
    #pragma unroll
    for (int r = 0; r < 2; r++) {
        const int lp = r*256 + t;
        const int p  = g*NPG_ + lp;
        const int c  = idx0[p];
        const int lc = c - g*CPG_;
        sx0[lp] = rgb[p];
        srx[lp] = pos[p*3+0] - pos1[c*3+0];
        sry[lp] = pos[p*3+1] - pos1[c*3+1];
        srz[lp] = pos[p*3+2] - pos1[c*3+2];
        slc1[lp] = (unsigned short)lc;
        atomicAdd(&cnt[lc], 1);
    }
    __syncthreads();

    // Phase B: exclusive prefix sum over cnt[128] (Hillis-Steele)
    if (t < CPG_) scan[t] = cnt[t];
    __syncthreads();
    #pragma unroll
    for (int d = 1; d < CPG_; d <<= 1) {
        int v = 0;
        if (t < CPG_ && t >= d) v = scan[t - d];
        __syncthreads();
        if (t < CPG_) scan[t] += v;
        __syncthreads();
    }
    if (t < CPG_) { const int s = scan[t] - cnt[t]; start[t] = s; ctr[t] = s; }
    __syncthreads();

    // Phase C: scatter point ids into cluster-sorted order (1 int atomic per point)
    #pragma unroll
    for (int r = 0; r < 2; r++) {
        const int lp = r*256 + t;
        const int slot = atomicAdd(&ctr[slc1[lp]], 1);
        order[slot] = (unsigned short)lp;
    }
    __syncthreads();

    // Phase D: 2 threads per cluster (8-ch halves), accumulate owned points, no atomics
    {
        const int c = t >> 1, ch0 = (t & 1) * 8;
        float wj[8], wx[8], wy[8], wz[8], bb2[8];
        #pragma unroll
        for (int j = 0; j < 8; j++) {
            wj[j] = W1l[ch0+j]; wx[j] = W1l[16+ch0+j];
            wy[j] = W1l[32+ch0+j]; wz[j] = W1l[48+ch0+j];
            bb2[j] = b1l[ch0+j];
        }
        float a[8];
        #pragma unroll
        for (int j = 0; j < 8; j++) a[j] = 0.f;
        const int n = cnt[c], base = start[c];
        for (int i = 0; i < n; i++) {
            const int lp = order[base + i];
            const float x0 = sx0[lp], rx = srx[lp], ry = sry[lp], rz = srz[lp];
            #pragma unroll
            for (int j = 0; j < 8; j++) {
                const float h = bb2[j] + x0*wj[j] + rx*wx[j] + ry*wy[j] + rz*wz[j];
                a[j] += celu_f(h);
            }
        }
        const float inv = 1.f / fmaxf((float)n, 1.f);
        #pragma unroll
        for (int j = 0; j < 8; j++) aggT[c*20 + ch0 + j] = a[j] * inv;
    }
    __syncthreads();

    // global conv: [128,16] @ [16,32] -> celu -> f1 (bf16)
    const int oc = t & 31;
    float wreg[16];
    #pragma unroll
    for (int j = 0; j < 16; j++) wreg[j] = sW1g[j*32 + oc];
    const float bg = b1g[oc];
    #pragma unroll
    for (int i = 0; i < 16; i++) {
        const int lc = (t >> 5) + i*8;
        float a = bg;
        #pragma unroll
        for (int j = 0; j < 16; j += 4) {
            const float4 a4 = *(const float4*)&aggT[lc*20 + j];
            a += a4.x*wreg[j] + a4.y*wreg[j+1] + a4.z*wreg[j+2] + a4.w*wreg[j+3];
        }
        f1[(size_t)(g*CPG_ + lc)*32 + oc] = f2bf(celu_f(a));
    }
}

// ---------------- conv2: f1(bf16) -> f2 [M2,128] bf16, one block per glimpse ----------------
// weights streamed from global (L1-resident), LDS holds only x + aggregation
__global__ __launch_bounds__(256, 6) void k_conv2(
    const unsigned short* __restrict__ f1, const float* __restrict__ pos1, const float* __restrict__ pos2,
    const int* __restrict__ idx1, const float* __restrict__ W2l, const float* __restrict__ b2l,
    const float* __restrict__ W2g, const float* __restrict__ b2g, unsigned short* __restrict__ f2)
{
    const int g = blockIdx.x, t = threadIdx.x;
    __shared__ __align__(16) unsigned short xs16[CPG_*40];  // 35 bf16 inputs + pad; 2-way banks
    __shared__ int   slc[CPG_];
    __shared__ float aggt[64*33];     // atomic target [ch*33 + slc]
    __shared__ float cnt[CPG2_];
    float* const aggr = (float*)xs16; // overlay: [r*68 + ch] (8704 B <= 10240 B), live after xs dead

    for (int i = t; i < 64*33; i += 256) aggt[i] = 0.f;
    if (t < CPG2_) cnt[t] = 0.f;
    {   // f1 glimpse tile: 4096 bf16 = 512 uint4; 2 uint4 (16 bf16) per thread
        const uint4 v0 = ((const uint4*)f1)[(size_t)g*512 + t*2];
        const uint4 v1 = ((const uint4*)f1)[(size_t)g*512 + t*2 + 1];
        const int row = t >> 1, col = (t & 1) * 16;
        *(uint4*)&xs16[row*40 + col]     = v0;
        *(uint4*)&xs16[row*40 + col + 8] = v1;
    }
    if (t < CPG_) {
        const int c2 = idx1[g*CPG_ + t];
        slc[t] = c2 - g*CPG2_;
        #pragma unroll
        for (int d = 0; d < 3; d++)
            xs16[t*40 + 32 + d] = f2bf(pos1[(g*CPG_ + t)*3 + d] - pos2[c2*3 + d]);
        xs16[t*40 + 35] = 0;
    }
    __syncthreads();

    // local conv: edges {eg+32i} x ch [8cg, 8cg+8); weights from global
    const int cg = t & 7, eg = t >> 3;
    const int ch0 = cg * 8;
    float acc[4][8];
    {
        const float4 bA = *(const float4*)&b2l[ch0];
        const float4 bB = *(const float4*)&b2l[ch0+4];
        #pragma unroll
        for (int i = 0; i < 4; i++) {
            acc[i][0]=bA.x; acc[i][1]=bA.y; acc[i][2]=bA.z; acc[i][3]=bA.w;
            acc[i][4]=bB.x; acc[i][5]=bB.y; acc[i][6]=bB.z; acc[i][7]=bB.w;
        }
    }
    #pragma unroll 1
    for (int kq = 0; kq < 8; kq++) {
        const int k = kq*4;
        uint2 xr[4];
        #pragma unroll
        for (int i = 0; i < 4; i++) xr[i] = *(const uint2*)&xs16[(eg + 32*i)*40 + k];
        #pragma unroll
        for (int dk = 0; dk < 4; dk++) {
            const float4 wA = *(const float4*)&W2l[(k+dk)*64 + ch0];
            const float4 wB = *(const float4*)&W2l[(k+dk)*64 + ch0 + 4];
            #pragma unroll
            for (int i = 0; i < 4; i++) {
                const float xv = bfsel(xr[i], dk);
                acc[i][0] += xv*wA.x; acc[i][1] += xv*wA.y; acc[i][2] += xv*wA.z; acc[i][3] += xv*wA.w;
                acc[i][4] += xv*wB.x; acc[i][5] += xv*wB.y; acc[i][6] += xv*wB.z; acc[i][7] += xv*wB.w;
            }
        }
    }
    {   // tail k = 32..34 (35 padded to 0)
        uint2 xr[4];
        #pragma unroll
        for (int i = 0; i < 4; i++) xr[i] = *(const uint2*)&xs16[(eg + 32*i)*40 + 32];
        #pragma unroll
        for (int dk = 0; dk < 3; dk++) {
            const float4 wA = *(const float4*)&W2l[(32+dk)*64 + ch0];
            const float4 wB = *(const float4*)&W2l[(32+dk)*64 + ch0 + 4];
            #pragma unroll
            for (int i = 0; i < 4; i++) {
                const float xv = bfsel(xr[i], dk);
                acc[i][0] += xv*wA.x; acc[i][1] += xv*wA.y; acc[i][2] += xv*wA.z; acc[i][3] += xv*wA.w;
                acc[i][4] += xv*wB.x; acc[i][5] += xv*wB.y; acc[i][6] += xv*wB.z; acc[i][7] += xv*wB.w;
            }
        }
    }
    #pragma unroll
    for (int i = 0; i < 4; i++) {
        const int s = slc[eg + 32*i];
        #pragma unroll
        for (int j = 0; j < 8; j++)
            atomicAdd(&aggt[(ch0 + j)*33 + s], celu_f(acc[i][j]));
    }
    if (t < CPG_) atomicAdd(&cnt[slc[t]], 1.f);
    __syncthreads();   // xs16 dead; aggr overlay becomes live

    #pragma unroll
    for (int ii = 0; ii < 8; ii++) {
        const int idx = t + 256*ii;
        const int r = idx >> 6, ch = idx & 63;
        aggr[r*68 + ch] = aggt[ch*33 + r] / fmaxf(cnt[r], 1.f);
    }
    __syncthreads();

    // global conv: [32,64] @ [64,128]; rows {rg+8i} x ch [4cg2, 4cg2+4); W2g from global
    const int cg2 = t & 31, rg = t >> 5;
    const int co = cg2 * 4;
    float acc2[4][4];
    {
        const float4 b4 = *(const float4*)&b2g[co];
        #pragma unroll
        for (int i = 0; i < 4; i++) { acc2[i][0]=b4.x; acc2[i][1]=b4.y; acc2[i][2]=b4.z; acc2[i][3]=b4.w; }
    }
    #pragma unroll 1
    for (int kq = 0; kq < 16; kq++) {
        const int k = kq*4;
        float4 xr[4];
        #pragma unroll
        for (int i = 0; i < 4; i++) xr[i] = *(const float4*)&aggr[(rg + 8*i)*68 + k];
        #pragma unroll
        for (int dk = 0; dk < 4; dk++) {
            const float4 w4 = *(const float4*)&W2g[(k+dk)*128 + co];
            #pragma unroll
            for (int i = 0; i < 4; i++) {
                const float xv = f4c(xr[i], dk);
                acc2[i][0] += xv*w4.x; acc2[i][1] += xv*w4.y; acc2[i][2] += xv*w4.z; acc2[i][3] += xv*w4.w;
            }
        }
    }
    #pragma unroll
    for (int i = 0; i < 4; i++) {
        const int r = rg + 8*i;
        const unsigned p0 = ((unsigned)f2bf(celu_f(acc2[i][1])) << 16) | f2bf(celu_f(acc2[i][0]));
        const unsigned p1 = ((unsigned)f2bf(celu_f(acc2[i][3])) << 16) | f2bf(celu_f(acc2[i][2]));
        *(uint2*)&f2[(size_t)(g*CPG2_ + r)*128 + co] = make_uint2(p0, p1);
    }
}

// ---------------- conv3 + linear + sample: 2 glimpses per block, f2 bf16 in ----------------
__global__ __launch_bounds__(256, 5) void k_conv3(
    const unsigned short* __restrict__ f2, const float* __restrict__ pos2,
    const float* __restrict__ W3l, const float* __restrict__ b3l,
    const float* __restrict__ W3g, const float* __restrict__ b3g,
    const float* __restrict__ Wlin, const float* __restrict__ blin,
    const float* __restrict__ eps, float* __restrict__ out)
{
    const int g0 = blockIdx.x * 2, t = threadIdx.x;
    __shared__ __align__(16) unsigned short xs16[64*136];  // 128 feat + 3 pos + pad; 2-way banks
    __shared__ float agg[256];
    __shared__ float f3s[512];
    __shared__ float outs[512];
    float* const red = (float*)xs16;   // overlay stride 132 (16896 B <= 17408 B)

    {   // stage f2 tile: 8192 bf16 = 1024 uint4; 4 uint4 (32 bf16) per thread
        const int row = t >> 2, col = (t & 3) * 32;
        const size_t base = (size_t)g0*512 + t*4;
        const uint4 v0 = ((const uint4*)f2)[base + 0];
        const uint4 v1 = ((const uint4*)f2)[base + 1];
        const uint4 v2 = ((const uint4*)f2)[base + 2];
        const uint4 v3 = ((const uint4*)f2)[base + 3];
        *(uint4*)&xs16[row*136 + col]      = v0;
        *(uint4*)&xs16[row*136 + col + 8]  = v1;
        *(uint4*)&xs16[row*136 + col + 16] = v2;
        *(uint4*)&xs16[row*136 + col + 24] = v3;
    }
    if (t < 64) {
        #pragma unroll
        for (int d = 0; d < 3; d++)
            xs16[t*136 + 128 + d] = f2bf(pos2[(g0*CPG2_ + t)*3 + d]);
        xs16[t*136 + 131] = 0;
    }
    __syncthreads();

    // local conv: rows {rg+16i} x ch [8cg, 8cg+8); W3l streamed (L2)
    const int cg = t & 15, rg = t >> 4;
    const int ch0 = cg * 8;
    float acc[4][8];
    {
        const float4 bA = *(const float4*)&b3l[ch0];
        const float4 bB = *(const float4*)&b3l[ch0+4];
        #pragma unroll
        for (int i = 0; i < 4; i++) {
            acc[i][0]=bA.x; acc[i][1]=bA.y; acc[i][2]=bA.z; acc[i][3]=bA.w;
            acc[i][4]=bB.x; acc[i][5]=bB.y; acc[i][6]=bB.z; acc[i][7]=bB.w;
        }
    }
    #pragma unroll 1
    for (int kq = 0; kq < 32; kq++) {
        const int k = kq*4;
        uint2 xr[4];
        #pragma unroll
        for (int i = 0; i < 4; i++) xr[i] = *(const uint2*)&xs16[(rg + 16*i)*136 + k];
        #pragma unroll
        for (int dk = 0; dk < 4; dk++) {
            const float4 wA = *(const float4*)&W3l[(k+dk)*128 + ch0];
            const float4 wB = *(const float4*)&W3l[(k+dk)*128 + ch0 + 4];
            #pragma unroll
            for (int i = 0; i < 4; i++) {
                const float xv = bfsel(xr[i], dk);
                acc[i][0] += xv*wA.x; acc[i][1] += xv*wA.y; acc[i][2] += xv*wA.z; acc[i][3] += xv*wA.w;
                acc[i][4] += xv*wB.x; acc[i][5] += xv*wB.y; acc[i][6] += xv*wB.z; acc[i][7] += xv*wB.w;
            }
        }
    }
    {   // tail k = 128..130 (131 padded to 0)
        uint2 xr[4];
        #pragma unroll
        for (int i = 0; i < 4; i++) xr[i] = *(const uint2*)&xs16[(rg + 16*i)*136 + 128];
        #pragma unroll
        for (int dk = 0; dk < 3; dk++) {
            const float4 wA = *(const float4*)&W3l[(128+dk)*128 + ch0];
            const float4 wB = *(const float4*)&W3l[(128+dk)*128 + ch0 + 4];
            #pragma unroll
            for (int i = 0; i < 4; i++) {
                const float xv = bfsel(xr[i], dk);
                acc[i][0] += xv*wA.x; acc[i][1] += xv*wA.y; acc[i][2] += xv*wA.z; acc[i][3] += xv*wA.w;
                acc[i][4] += xv*wB.x; acc[i][5] += xv*wB.y; acc[i][6] += xv*wB.z; acc[i][7] += xv*wB.w;
            }
        }
    }
    float s0[8], s1[8];
    #pragma unroll
    for (int j = 0; j < 8; j++) {
        s0[j] = celu_f(acc[0][j]) + celu_f(acc[1][j]);
        s1[j] = celu_f(acc[2][j]) + celu_f(acc[3][j]);
    }
    __syncthreads();   // xs16 dead; red overlay becomes live
    *(float4*)&red[rg*132 + ch0]          = make_float4(s0[0], s0[1], s0[2], s0[3]);
    *(float4*)&red[rg*132 + ch0 + 4]      = make_float4(s0[4], s0[5], s0[6], s0[7]);
    *(float4*)&red[(16+rg)*132 + ch0]     = make_float4(s1[0], s1[1], s1[2], s1[3]);
    *(float4*)&red[(16+rg)*132 + ch0 + 4] = make_float4(s1[4], s1[5], s1[6], s1[7]);
    __syncthreads();
    {
        const int gl = t >> 7, ch = t & 127;
        float a = 0.f;
        #pragma unroll
        for (int r2 = 0; r2 < 16; r2++) a += red[(gl*16 + r2)*132 + ch];
        agg[gl*128 + ch] = a * (1.f/32.f);
    }
    __syncthreads();

    // global conv: agg[128] @ W3g[128,256] + b3g -> celu -> f3
    {
        float a0 = b3g[t], a1 = a0;
        #pragma unroll 2
        for (int k = 0; k < 128; k += 4) {
            const float4 ga = *(const float4*)&agg[k];
            const float4 gb = *(const float4*)&agg[128 + k];
            const float w0 = W3g[(k+0)*256+t], w1 = W3g[(k+1)*256+t];
            const float w2 = W3g[(k+2)*256+t], w3 = W3g[(k+3)*256+t];
            a0 += ga.x*w0 + ga.y*w1 + ga.z*w2 + ga.w*w3;
            a1 += gb.x*w0 + gb.y*w1 + gb.z*w2 + gb.w*w3;
        }
        f3s[t]       = celu_f(a0);
        f3s[256 + t] = celu_f(a1);
    }
    __syncthreads();

    // linear head: f3[256] @ Wlin[256,256] + blin
    {
        float a0 = blin[t], a1 = a0;
        #pragma unroll 2
        for (int k = 0; k < 256; k += 4) {
            const float4 fa = *(const float4*)&f3s[k];
            const float4 fb = *(const float4*)&f3s[256 + k];
            const float w0 = Wlin[(k+0)*256+t], w1 = Wlin[(k+1)*256+t];
            const float w2 = Wlin[(k+2)*256+t], w3 = Wlin[(k+3)*256+t];
            a0 += fa.x*w0 + fa.y*w1 + fa.z*w2 + fa.w*w3;
            a1 += fb.x*w0 + fb.y*w1 + fb.z*w2 + fb.w*w3;
        }
        outs[t]       = a0;
        outs[256 + t] = a1;
    }
    out[OFF_F + (size_t)g0*256 + t]     = f3s[t];
    out[OFF_F + (size_t)(g0+1)*256 + t] = f3s[256 + t];
    __syncthreads();

    if (t < 128) {
        #pragma unroll
        for (int gl = 0; gl < 2; gl++) {
            const int g = g0 + gl;
            const float mu    = outs[gl*256 + t];
            const float sigma = softplus_f(outs[gl*256 + 128 + t]);
            const float z     = mu + sigma * eps[g*128 + t];
            out[OFF_MU + g*128 + t] = mu;
            out[OFF_SG + g*128 + t] = sigma;
            if (t < 64) out[OFF_ZW + g*64 + t] = z;
            else        out[OFF_ZM + g*64 + (t - 64)] = z;
        }
    }
}

extern "C" void kernel_launch(void* const* d_in, const int* in_sizes, int n_in,
                              void* d_out, int out_size, void* d_ws, size_t ws_size,
                              hipStream_t stream)
{
    const float* rgb  = (const float*)d_in[0];
    const float* pos  = (const float*)d_in[1];
    const float* pos1 = (const float*)d_in[2];
    const float* pos2 = (const float*)d_in[3];
    const int*   idx0 = (const int*)d_in[4];
    const int*   idx1 = (const int*)d_in[5];
    const float* eps  = (const float*)d_in[7];
    const float* W1l = (const float*)d_in[8],  *b1l = (const float*)d_in[9];
    const float* W1g = (const float*)d_in[10], *b1g = (const float*)d_in[11];
    const float* W2l = (const float*)d_in[12], *b2l = (const float*)d_in[13];
    const float* W2g = (const float*)d_in[14], *b2g = (const float*)d_in[15];
    const float* W3l = (const float*)d_in[16], *b3l = (const float*)d_in[17];
    const float* W3g = (const float*)d_in[18], *b3g = (const float*)d_in[19];
    const float* Wlin = (const float*)d_in[20], *blin = (const float*)d_in[21];

    unsigned short* f1 = (unsigned short*)d_ws;          // M1*32 bf16
    unsigned short* f2 = f1 + (size_t)M1_*32;            // M2*128 bf16
    float* outp = (float*)d_out;

    k_conv1<<<G_,   256, 0, stream>>>(rgb, pos, pos1, idx0, W1l, b1l, W1g, b1g, f1);
    k_conv2<<<G_,   256, 0, stream>>>(f1, pos1, pos2, idx1, W2l, b2l, W2g, b2g, f2);
    k_conv3<<<G_/2, 256, 0, stream>>>(f2, pos2, W3l, b3l, W3g, b3g, Wlin, blin, eps, outp);
}

// Round 7
// 256.440 us; speedup vs baseline: 2.1313x; 1.1504x over previous
//
#include <hip/hip_runtime.h>
#include <hip/hip_bf16.h>
#include <cstddef>

#define G_   2048
#define NPG_ 512
#define CPG_ 128
#define CPG2_ 32
#define N0_  (G_*NPG_)
#define M1_  (G_*CPG_)
#define M2_  (G_*CPG2_)

// output layout (floats): z_what[G,64] | z_mask[G,64] | mu[G,128] | sigma[G,128] | f[G,256]
#define OFF_ZW 0
#define OFF_ZM (G_*64)
#define OFF_MU (2*G_*64)
#define OFF_SG (2*G_*64 + G_*128)
#define OFF_F  (2*G_*64 + 2*G_*128)

typedef __attribute__((ext_vector_type(8))) short bf16x8;
typedef __attribute__((ext_vector_type(4))) float f32x4;

__device__ __forceinline__ float celu_f(float x)     { return x > 0.f ? x : __expf(x) - 1.f; }
__device__ __forceinline__ float softplus_f(float x) { return fmaxf(x, 0.f) + __logf(1.f + __expf(-fabsf(x))); }
__device__ __forceinline__ unsigned short f2bf(float x) {
    __hip_bfloat16 h = __float2bfloat16(x);
    return *reinterpret_cast<unsigned short*>(&h);
}

// ---------------- prep: transposed, zero-K-padded bf16 weight copies in ws ----------------
__global__ void k_prep(const float* __restrict__ W2l, const float* __restrict__ W2g,
                       const float* __restrict__ W3l,
                       unsigned short* __restrict__ w2lT, unsigned short* __restrict__ w2gT,
                       unsigned short* __restrict__ w3lT)
{
    const int tid = blockIdx.x*256 + threadIdx.x, stride = gridDim.x*256;
    for (int i = tid; i < 64*64; i += stride) {          // W2l [35,64] -> [ch=64][k=64]
        const int ch = i >> 6, k = i & 63;
        w2lT[i] = f2bf(k < 35 ? W2l[k*64 + ch] : 0.f);
    }
    for (int i = tid; i < 128*64; i += stride) {         // W2g [64,128] -> [ch=128][k=64]
        const int ch = i >> 6, k = i & 63;
        w2gT[i] = f2bf(W2g[k*128 + ch]);
    }
    for (int i = tid; i < 128*160; i += stride) {        // W3l [131,128] -> [ch=128][k=160]
        const int ch = i / 160, k = i % 160;
        w3lT[i] = f2bf(k < 131 ? W3l[k*128 + ch] : 0.f);
    }
}

// ---------------- conv1: counting-sort per glimpse, zero fp atomics (unchanged) ----------------
__global__ __launch_bounds__(256, 6) void k_conv1(
    const float* __restrict__ rgb, const float* __restrict__ pos, const float* __restrict__ pos1,
    const int* __restrict__ idx0, const float* __restrict__ W1l, const float* __restrict__ b1l,
    const float* __restrict__ W1g, const float* __restrict__ b1g, unsigned short* __restrict__ f1)
{
    const int g = blockIdx.x, t = threadIdx.x;
    __shared__ float sx0[NPG_], srx[NPG_], sry[NPG_], srz[NPG_];
    __shared__ unsigned short slc1[NPG_], order[NPG_];
    __shared__ int cnt[CPG_], start[CPG_], ctr[CPG_], scan[CPG_];
    __shared__ float aggT[CPG_*20];
    __shared__ float sW1g[512];

    for (int i = t; i < 512; i += 256) sW1g[i] = W1g[i];
    if (t < CPG_) cnt[t] = 0;
    __syncthreads();

    #pragma unroll
    for (int r = 0; r < 2; r++) {
        const int lp = r*256 + t;
        const int p  = g*NPG_ + lp;
        const int c  = idx0[p];
        const int lc = c - g*CPG_;
        sx0[lp] = rgb[p];
        srx[lp] = pos[p*3+0] - pos1[c*3+0];
        sry[lp] = pos[p*3+1] - pos1[c*3+1];
        srz[lp] = pos[p*3+2] - pos1[c*3+2];
        slc1[lp] = (unsigned short)lc;
        atomicAdd(&cnt[lc], 1);
    }
    __syncthreads();

    if (t < CPG_) scan[t] = cnt[t];
    __syncthreads();
    #pragma unroll
    for (int d = 1; d < CPG_; d <<= 1) {
        int v = 0;
        if (t < CPG_ && t >= d) v = scan[t - d];
        __syncthreads();
        if (t < CPG_) scan[t] += v;
        __syncthreads();
    }
    if (t < CPG_) { const int s = scan[t] - cnt[t]; start[t] = s; ctr[t] = s; }
    __syncthreads();

    #pragma unroll
    for (int r = 0; r < 2; r++) {
        const int lp = r*256 + t;
        const int slot = atomicAdd(&ctr[slc1[lp]], 1);
        order[slot] = (unsigned short)lp;
    }
    __syncthreads();

    {
        const int c = t >> 1, ch0 = (t & 1) * 8;
        float wj[8], wx[8], wy[8], wz[8], bb2[8];
        #pragma unroll
        for (int j = 0; j < 8; j++) {
            wj[j] = W1l[ch0+j]; wx[j] = W1l[16+ch0+j];
            wy[j] = W1l[32+ch0+j]; wz[j] = W1l[48+ch0+j];
            bb2[j] = b1l[ch0+j];
        }
        float a[8];
        #pragma unroll
        for (int j = 0; j < 8; j++) a[j] = 0.f;
        const int n = cnt[c], base = start[c];
        for (int i = 0; i < n; i++) {
            const int lp = order[base + i];
            const float x0 = sx0[lp], rx = srx[lp], ry = sry[lp], rz = srz[lp];
            #pragma unroll
            for (int j = 0; j < 8; j++) {
                const float h = bb2[j] + x0*wj[j] + rx*wx[j] + ry*wy[j] + rz*wz[j];
                a[j] += celu_f(h);
            }
        }
        const float inv = 1.f / fmaxf((float)n, 1.f);
        #pragma unroll
        for (int j = 0; j < 8; j++) aggT[c*20 + ch0 + j] = a[j] * inv;
    }
    __syncthreads();

    const int oc = t & 31;
    float wreg[16];
    #pragma unroll
    for (int j = 0; j < 16; j++) wreg[j] = sW1g[j*32 + oc];
    const float bg = b1g[oc];
    #pragma unroll
    for (int i = 0; i < 16; i++) {
        const int lc = (t >> 5) + i*8;
        float a = bg;
        #pragma unroll
        for (int j = 0; j < 16; j += 4) {
            const float4 a4 = *(const float4*)&aggT[lc*20 + j];
            a += a4.x*wreg[j] + a4.y*wreg[j+1] + a4.z*wreg[j+2] + a4.w*wreg[j+3];
        }
        f1[(size_t)(g*CPG_ + lc)*32 + oc] = f2bf(celu_f(a));
    }
}

// ---------------- conv2: MFMA. local [128x64,K35->64], global [32x128,K64] ----------------
__global__ __launch_bounds__(256, 5) void k_conv2(
    const unsigned short* __restrict__ f1, const float* __restrict__ pos1, const float* __restrict__ pos2,
    const int* __restrict__ idx1, const unsigned short* __restrict__ w2lT, const float* __restrict__ b2l,
    const unsigned short* __restrict__ w2gT, const float* __restrict__ b2g, unsigned short* __restrict__ f2)
{
    const int g = blockIdx.x, t = threadIdx.x;
    const int lane = t & 63, wv = t >> 6;
    const int lr = lane & 15, quad = lane >> 4;
    __shared__ __align__(16) unsigned short xs16[CPG_*72];  // K padded to 64 (cols 35..71 zero)
    __shared__ float aggt[64*33];
    __shared__ float cnt[CPG2_];
    __shared__ int   slc[CPG_];
    unsigned short* const agg2 = xs16;   // overlay: [32 rows][72], bf16, live after xs dead

    for (int i = t; i < 64*33; i += 256) aggt[i] = 0.f;
    if (t < CPG2_) cnt[t] = 0.f;
    {   // stage f1 tile (cols 0..31)
        const uint4 v0 = ((const uint4*)f1)[(size_t)g*512 + t*2];
        const uint4 v1 = ((const uint4*)f1)[(size_t)g*512 + t*2 + 1];
        const int row = t >> 1, col = (t & 1) * 16;
        *(uint4*)&xs16[row*72 + col]     = v0;
        *(uint4*)&xs16[row*72 + col + 8] = v1;
    }
    for (int i = t; i < 128*37; i += 256) {   // zero cols 35..71
        const int r = i / 37, c = 35 + (i - r*37);
        xs16[r*72 + c] = 0;
    }
    if (t < CPG_) {                            // rel pos cols 32..34
        const int c2 = idx1[g*CPG_ + t];
        slc[t] = c2 - g*CPG2_;
        #pragma unroll
        for (int d = 0; d < 3; d++)
            xs16[t*72 + 32 + d] = f2bf(pos1[(g*CPG_ + t)*3 + d] - pos2[c2*3 + d]);
    }
    __syncthreads();

    // local conv MFMA: wave wv owns n-tile wv (channels wv*16 + lr)
    {
        const int chn = wv*16 + lr;
        bf16x8 bw0 = *(const bf16x8*)&w2lT[chn*64 + quad*8];
        bf16x8 bw1 = *(const bf16x8*)&w2lT[chn*64 + 32 + quad*8];
        const float bias = b2l[chn];
        f32x4 acc[8];
        #pragma unroll
        for (int m = 0; m < 8; m++) acc[m] = (f32x4){bias, bias, bias, bias};
        #pragma unroll
        for (int m = 0; m < 8; m++) {
            const int e = m*16 + lr;
            bf16x8 a0 = *(const bf16x8*)&xs16[e*72 + quad*8];
            bf16x8 a1 = *(const bf16x8*)&xs16[e*72 + 32 + quad*8];
            acc[m] = __builtin_amdgcn_mfma_f32_16x16x32_bf16(a0, bw0, acc[m], 0, 0, 0);
            acc[m] = __builtin_amdgcn_mfma_f32_16x16x32_bf16(a1, bw1, acc[m], 0, 0, 0);
        }
        // celu + aggregate (C layout: row=quad*4+r, col=lr)
        #pragma unroll
        for (int m = 0; m < 8; m++) {
            #pragma unroll
            for (int r = 0; r < 4; r++) {
                const int e = m*16 + quad*4 + r;
                atomicAdd(&aggt[chn*33 + slc[e]], celu_f(acc[m][r]));
            }
        }
    }
    if (t < CPG_) atomicAdd(&cnt[slc[t]], 1.f);
    __syncthreads();   // xs16 reads done; agg2 overlay becomes live

    for (int i = t; i < 2048; i += 256) {
        const int r = i >> 6, ch = i & 63;
        agg2[r*72 + ch] = f2bf(aggt[ch*33 + r] / fmaxf(cnt[r], 1.f));
    }
    __syncthreads();

    // global conv MFMA: [32x64]@[64x128]; wave owns n-tiles {wv, wv+4}
    {
        f32x4 acc2[2][2];
        int   chn2[2];
        bf16x8 bw[2][2];
        #pragma unroll
        for (int nt = 0; nt < 2; nt++) {
            chn2[nt] = (wv + nt*4)*16 + lr;
            const float bias = b2g[chn2[nt]];
            #pragma unroll
            for (int mt = 0; mt < 2; mt++) acc2[nt][mt] = (f32x4){bias, bias, bias, bias};
            bw[nt][0] = *(const bf16x8*)&w2gT[chn2[nt]*64 + quad*8];
            bw[nt][1] = *(const bf16x8*)&w2gT[chn2[nt]*64 + 32 + quad*8];
        }
        #pragma unroll
        for (int ks = 0; ks < 2; ks++) {
            #pragma unroll
            for (int mt = 0; mt < 2; mt++) {
                bf16x8 a = *(const bf16x8*)&agg2[(mt*16 + lr)*72 + ks*32 + quad*8];
                acc2[0][mt] = __builtin_amdgcn_mfma_f32_16x16x32_bf16(a, bw[0][ks], acc2[0][mt], 0, 0, 0);
                acc2[1][mt] = __builtin_amdgcn_mfma_f32_16x16x32_bf16(a, bw[1][ks], acc2[1][mt], 0, 0, 0);
            }
        }
        #pragma unroll
        for (int nt = 0; nt < 2; nt++)
        #pragma unroll
        for (int mt = 0; mt < 2; mt++)
        #pragma unroll
        for (int r = 0; r < 4; r++) {
            const int row = mt*16 + quad*4 + r;
            f2[(size_t)(g*CPG2_ + row)*128 + chn2[nt]] = f2bf(celu_f(acc2[nt][mt][r]));
        }
    }
}

// ---------------- conv3 (MFMA local) + gemvs + sample: 2 glimpses per block ----------------
__global__ __launch_bounds__(256, 4) void k_conv3(
    const unsigned short* __restrict__ f2, const float* __restrict__ pos2,
    const unsigned short* __restrict__ w3lT, const float* __restrict__ b3l,
    const float* __restrict__ W3g, const float* __restrict__ b3g,
    const float* __restrict__ Wlin, const float* __restrict__ blin,
    const float* __restrict__ eps, float* __restrict__ out)
{
    const int g0 = blockIdx.x * 2, t = threadIdx.x;
    const int lane = t & 63, wv = t >> 6;
    const int lr = lane & 15, quad = lane >> 4;
    __shared__ __align__(16) unsigned short xs16[64*168];  // K padded to 160 (cols 131..167 zero)
    __shared__ float red2[2*128*9];
    __shared__ float agg[256];
    __shared__ float f3s[512];
    __shared__ float outs[512];

    {   // stage f2 tile: row = t>>2, cols (t&3)*32 .. +31
        const int row = t >> 2, q = t & 3;
        const size_t base = (size_t)(g0*CPG2_ + row)*16 + q*4;   // uint4 units
        const uint4 v0 = ((const uint4*)f2)[base + 0];
        const uint4 v1 = ((const uint4*)f2)[base + 1];
        const uint4 v2 = ((const uint4*)f2)[base + 2];
        const uint4 v3 = ((const uint4*)f2)[base + 3];
        *(uint4*)&xs16[row*168 + q*32]      = v0;
        *(uint4*)&xs16[row*168 + q*32 + 8]  = v1;
        *(uint4*)&xs16[row*168 + q*32 + 16] = v2;
        *(uint4*)&xs16[row*168 + q*32 + 24] = v3;
    }
    for (int i = t; i < 64*37; i += 256) {   // zero cols 131..167
        const int r = i / 37, c = 131 + (i - r*37);
        xs16[r*168 + c] = 0;
    }
    if (t < 64) {                             // pos cols 128..130 (centers are zeros: rel = pos2)
        #pragma unroll
        for (int d = 0; d < 3; d++)
            xs16[t*168 + 128 + d] = f2bf(pos2[(g0*CPG2_ + t)*3 + d]);
    }
    __syncthreads();

    // local conv MFMA: M=64 (4 m-tiles), N=128 (wave owns n-tiles {wv, wv+4}), K=160 (5 steps)
    {
        f32x4 acc[2][4];
        int chn[2];
        #pragma unroll
        for (int nt = 0; nt < 2; nt++) {
            chn[nt] = (wv + nt*4)*16 + lr;
            const float bias = b3l[chn[nt]];
            #pragma unroll
            for (int mt = 0; mt < 4; mt++) acc[nt][mt] = (f32x4){bias, bias, bias, bias};
        }
        #pragma unroll
        for (int ks = 0; ks < 5; ks++) {
            bf16x8 b0 = *(const bf16x8*)&w3lT[chn[0]*160 + ks*32 + quad*8];
            bf16x8 b1 = *(const bf16x8*)&w3lT[chn[1]*160 + ks*32 + quad*8];
            #pragma unroll
            for (int mt = 0; mt < 4; mt++) {
                bf16x8 a = *(const bf16x8*)&xs16[(mt*16 + lr)*168 + ks*32 + quad*8];
                acc[0][mt] = __builtin_amdgcn_mfma_f32_16x16x32_bf16(a, b0, acc[0][mt], 0, 0, 0);
                acc[1][mt] = __builtin_amdgcn_mfma_f32_16x16x32_bf16(a, b1, acc[1][mt], 0, 0, 0);
            }
        }
        // celu + partial row-sums: tile rows quad*4..+3 of m-tile mt; glimpse = mt>>1
        #pragma unroll
        for (int nt = 0; nt < 2; nt++)
        #pragma unroll
        for (int mt = 0; mt < 4; mt++) {
            float p = celu_f(acc[nt][mt][0]) + celu_f(acc[nt][mt][1])
                    + celu_f(acc[nt][mt][2]) + celu_f(acc[nt][mt][3]);
            const int gl = mt >> 1, pidx = (mt & 1)*4 + quad;
            red2[(gl*128 + chn[nt])*9 + pidx] = p;
        }
    }
    __syncthreads();
    {   // reduce 8 partials per (glimpse, ch); /32 for mean
        const int gl = t >> 7, ch = t & 127;
        const float* rp = &red2[(gl*128 + ch)*9];
        float a = 0.f;
        #pragma unroll
        for (int p = 0; p < 8; p++) a += rp[p];
        agg[gl*128 + ch] = a * (1.f/32.f);
    }
    __syncthreads();

    // global conv: agg[128] @ W3g[128,256] + b3g -> celu -> f3 (both glimpses share w)
    {
        float a0 = b3g[t], a1 = a0;
        #pragma unroll 2
        for (int k = 0; k < 128; k += 4) {
            const float4 ga = *(const float4*)&agg[k];
            const float4 gb = *(const float4*)&agg[128 + k];
            const float w0 = W3g[(k+0)*256+t], w1 = W3g[(k+1)*256+t];
            const float w2 = W3g[(k+2)*256+t], w3 = W3g[(k+3)*256+t];
            a0 += ga.x*w0 + ga.y*w1 + ga.z*w2 + ga.w*w3;
            a1 += gb.x*w0 + gb.y*w1 + gb.z*w2 + gb.w*w3;
        }
        f3s[t]       = celu_f(a0);
        f3s[256 + t] = celu_f(a1);
    }
    __syncthreads();

    // linear head: f3[256] @ Wlin[256,256] + blin
    {
        float a0 = blin[t], a1 = a0;
        #pragma unroll 2
        for (int k = 0; k < 256; k += 4) {
            const float4 fa = *(const float4*)&f3s[k];
            const float4 fb = *(const float4*)&f3s[256 + k];
            const float w0 = Wlin[(k+0)*256+t], w1 = Wlin[(k+1)*256+t];
            const float w2 = Wlin[(k+2)*256+t], w3 = Wlin[(k+3)*256+t];
            a0 += fa.x*w0 + fa.y*w1 + fa.z*w2 + fa.w*w3;
            a1 += fb.x*w0 + fb.y*w1 + fb.z*w2 + fb.w*w3;
        }
        outs[t]       = a0;
        outs[256 + t] = a1;
    }
    out[OFF_F + (size_t)g0*256 + t]     = f3s[t];
    out[OFF_F + (size_t)(g0+1)*256 + t] = f3s[256 + t];
    __syncthreads();

    if (t < 128) {
        #pragma unroll
        for (int gl = 0; gl < 2; gl++) {
            const int g = g0 + gl;
            const float mu    = outs[gl*256 + t];
            const float sigma = softplus_f(outs[gl*256 + 128 + t]);
            const float z     = mu + sigma * eps[g*128 + t];
            out[OFF_MU + g*128 + t] = mu;
            out[OFF_SG + g*128 + t] = sigma;
            if (t < 64) out[OFF_ZW + g*64 + t] = z;
            else        out[OFF_ZM + g*64 + (t - 64)] = z;
        }
    }
}

extern "C" void kernel_launch(void* const* d_in, const int* in_sizes, int n_in,
                              void* d_out, int out_size, void* d_ws, size_t ws_size,
                              hipStream_t stream)
{
    const float* rgb  = (const float*)d_in[0];
    const float* pos  = (const float*)d_in[1];
    const float* pos1 = (const float*)d_in[2];
    const float* pos2 = (const float*)d_in[3];
    const int*   idx0 = (const int*)d_in[4];
    const int*   idx1 = (const int*)d_in[5];
    const float* eps  = (const float*)d_in[7];
    const float* W1l = (const float*)d_in[8],  *b1l = (const float*)d_in[9];
    const float* W1g = (const float*)d_in[10], *b1g = (const float*)d_in[11];
    const float* W2l = (const float*)d_in[12], *b2l = (const float*)d_in[13];
    const float* W2g = (const float*)d_in[14], *b2g = (const float*)d_in[15];
    const float* W3l = (const float*)d_in[16], *b3l = (const float*)d_in[17];
    const float* W3g = (const float*)d_in[18], *b3g = (const float*)d_in[19];
    const float* Wlin = (const float*)d_in[20], *blin = (const float*)d_in[21];

    unsigned short* f1   = (unsigned short*)d_ws;        // M1*32 bf16
    unsigned short* f2   = f1 + (size_t)M1_*32;          // M2*128 bf16
    unsigned short* w2lT = f2 + (size_t)M2_*128;         // 64*64
    unsigned short* w2gT = w2lT + 64*64;                 // 128*64
    unsigned short* w3lT = w2gT + 128*64;                // 128*160
    float* outp = (float*)d_out;

    k_prep <<<32,   256, 0, stream>>>(W2l, W2g, W3l, w2lT, w2gT, w3lT);
    k_conv1<<<G_,   256, 0, stream>>>(rgb, pos, pos1, idx0, W1l, b1l, W1g, b1g, f1);
    k_conv2<<<G_,   256, 0, stream>>>(f1, pos1, pos2, idx1, w2lT, b2l, w2gT, b2g, f2);
    k_conv3<<<G_/2, 256, 0, stream>>>(f2, pos2, w3lT, b3l, W3g, b3g, Wlin, blin, eps, outp);
}

// Round 9
// 174.028 us; speedup vs baseline: 3.1405x; 1.4736x over previous
//
#include <hip/hip_runtime.h>
#include <hip/hip_bf16.h>
#include <cstddef>

#define G_   2048
#define NPG_ 512
#define CPG_ 128
#define CPG2_ 32
#define N0_  (G_*NPG_)
#define M1_  (G_*CPG_)
#define M2_  (G_*CPG2_)

// output layout (floats): z_what[G,64] | z_mask[G,64] | mu[G,128] | sigma[G,128] | f[G,256]
#define OFF_ZW 0
#define OFF_ZM (G_*64)
#define OFF_MU (2*G_*64)
#define OFF_SG (2*G_*64 + G_*128)
#define OFF_F  (2*G_*64 + 2*G_*128)

typedef __attribute__((ext_vector_type(8))) short bf16x8;
typedef __attribute__((ext_vector_type(4))) float f32x4;

__device__ __forceinline__ float celu_f(float x)     { return x > 0.f ? x : __expf(x) - 1.f; }
__device__ __forceinline__ float softplus_f(float x) { return fmaxf(x, 0.f) + __logf(1.f + __expf(-fabsf(x))); }
__device__ __forceinline__ unsigned short f2bf(float x) {
    __hip_bfloat16 h = __float2bfloat16(x);
    return *reinterpret_cast<unsigned short*>(&h);
}

// ---------------- prep: transposed, zero-K-padded bf16 weight copies in ws ----------------
__global__ void k_prep(const float* __restrict__ W2l, const float* __restrict__ W2g,
                       const float* __restrict__ W3l,
                       unsigned short* __restrict__ w2lT, unsigned short* __restrict__ w2gT,
                       unsigned short* __restrict__ w3lT)
{
    const int tid = blockIdx.x*256 + threadIdx.x, stride = gridDim.x*256;
    for (int i = tid; i < 64*64; i += stride) {          // W2l [35,64] -> [ch=64][k=64]
        const int ch = i >> 6, k = i & 63;
        w2lT[i] = f2bf(k < 35 ? W2l[k*64 + ch] : 0.f);
    }
    for (int i = tid; i < 128*64; i += stride) {         // W2g [64,128] -> [ch=128][k=64]
        const int ch = i >> 6, k = i & 63;
        w2gT[i] = f2bf(W2g[k*128 + ch]);
    }
    for (int i = tid; i < 128*160; i += stride) {        // W3l [131,128] -> [ch=128][k=160]
        const int ch = i / 160, k = i % 160;
        w3lT[i] = f2bf(k < 131 ? W3l[k*128 + ch] : 0.f);
    }
}

// ---------------- conv1: counting-sort per glimpse, int atomics only (unchanged) ----------------
__global__ __launch_bounds__(256, 6) void k_conv1(
    const float* __restrict__ rgb, const float* __restrict__ pos, const float* __restrict__ pos1,
    const int* __restrict__ idx0, const float* __restrict__ W1l, const float* __restrict__ b1l,
    const float* __restrict__ W1g, const float* __restrict__ b1g, unsigned short* __restrict__ f1)
{
    const int g = blockIdx.x, t = threadIdx.x;
    __shared__ float sx0[NPG_], srx[NPG_], sry[NPG_], srz[NPG_];
    __shared__ unsigned short slc1[NPG_], order[NPG_];
    __shared__ int cnt[CPG_], start[CPG_], ctr[CPG_], scan[CPG_];
    __shared__ float aggT[CPG_*20];
    __shared__ float sW1g[512];

    for (int i = t; i < 512; i += 256) sW1g[i] = W1g[i];
    if (t < CPG_) cnt[t] = 0;
    __syncthreads();

    #pragma unroll
    for (int r = 0; r < 2; r++) {
        const int lp = r*256 + t;
        const int p  = g*NPG_ + lp;
        const int c  = idx0[p];
        const int lc = c - g*CPG_;
        sx0[lp] = rgb[p];
        srx[lp] = pos[p*3+0] - pos1[c*3+0];
        sry[lp] = pos[p*3+1] - pos1[c*3+1];
        srz[lp] = pos[p*3+2] - pos1[c*3+2];
        slc1[lp] = (unsigned short)lc;
        atomicAdd(&cnt[lc], 1);
    }
    __syncthreads();

    if (t < CPG_) scan[t] = cnt[t];
    __syncthreads();
    #pragma unroll
    for (int d = 1; d < CPG_; d <<= 1) {
        int v = 0;
        if (t < CPG_ && t >= d) v = scan[t - d];
        __syncthreads();
        if (t < CPG_) scan[t] += v;
        __syncthreads();
    }
    if (t < CPG_) { const int s = scan[t] - cnt[t]; start[t] = s; ctr[t] = s; }
    __syncthreads();

    #pragma unroll
    for (int r = 0; r < 2; r++) {
        const int lp = r*256 + t;
        const int slot = atomicAdd(&ctr[slc1[lp]], 1);
        order[slot] = (unsigned short)lp;
    }
    __syncthreads();

    {
        const int c = t >> 1, ch0 = (t & 1) * 8;
        float wj[8], wx[8], wy[8], wz[8], bb2[8];
        #pragma unroll
        for (int j = 0; j < 8; j++) {
            wj[j] = W1l[ch0+j]; wx[j] = W1l[16+ch0+j];
            wy[j] = W1l[32+ch0+j]; wz[j] = W1l[48+ch0+j];
            bb2[j] = b1l[ch0+j];
        }
        float a[8];
        #pragma unroll
        for (int j = 0; j < 8; j++) a[j] = 0.f;
        const int n = cnt[c], base = start[c];
        for (int i = 0; i < n; i++) {
            const int lp = order[base + i];
            const float x0 = sx0[lp], rx = srx[lp], ry = sry[lp], rz = srz[lp];
            #pragma unroll
            for (int j = 0; j < 8; j++) {
                const float h = bb2[j] + x0*wj[j] + rx*wx[j] + ry*wy[j] + rz*wz[j];
                a[j] += celu_f(h);
            }
        }
        const float inv = 1.f / fmaxf((float)n, 1.f);
        #pragma unroll
        for (int j = 0; j < 8; j++) aggT[c*20 + ch0 + j] = a[j] * inv;
    }
    __syncthreads();

    const int oc = t & 31;
    float wreg[16];
    #pragma unroll
    for (int j = 0; j < 16; j++) wreg[j] = sW1g[j*32 + oc];
    const float bg = b1g[oc];
    #pragma unroll
    for (int i = 0; i < 16; i++) {
        const int lc = (t >> 5) + i*8;
        float a = bg;
        #pragma unroll
        for (int j = 0; j < 16; j += 4) {
            const float4 a4 = *(const float4*)&aggT[lc*20 + j];
            a += a4.x*wreg[j] + a4.y*wreg[j+1] + a4.z*wreg[j+2] + a4.w*wreg[j+3];
        }
        f1[(size_t)(g*CPG_ + lc)*32 + oc] = f2bf(celu_f(a));
    }
}

// ---------------- conv2: MFMA local + MFMA segment-sum (one-hot S) + MFMA global ----------------
__global__ __launch_bounds__(256, 5) void k_conv2(
    const unsigned short* __restrict__ f1, const float* __restrict__ pos1, const float* __restrict__ pos2,
    const int* __restrict__ idx1, const unsigned short* __restrict__ w2lT, const float* __restrict__ b2l,
    const unsigned short* __restrict__ w2gT, const float* __restrict__ b2g, unsigned short* __restrict__ f2)
{
    const int g = blockIdx.x, t = threadIdx.x;
    const int lane = t & 63, wv = t >> 6;
    const int lr = lane & 15, quad = lane >> 4;
    __shared__ __align__(16) unsigned short xs16[CPG_*72];   // 18432 B; HT overlay after local conv
    __shared__ __align__(16) unsigned short sT[32*136];      // 8704 B one-hot S^T; agg2 overlay after
    __shared__ int   slc[CPG_];
    __shared__ int   cnti[CPG2_];
    __shared__ float invc[CPG2_];
    unsigned short* const HT   = xs16;   // [ch=64][e=128], stride 136 (17408 B <= 18432)
    unsigned short* const agg2 = sT;     // [s=32][ch=64],  stride 72  (4608 B  <= 8704)

    // P0: zero S^T, init cnt, stage x (f1 tile + relpos, K-pad cols 35..63)
    for (int i = t; i < 1088; i += 256) ((uint2*)sT)[i] = make_uint2(0u, 0u);
    if (t < CPG2_) cnti[t] = 0;
    {
        const uint4 v0 = ((const uint4*)f1)[(size_t)g*512 + t*2];
        const uint4 v1 = ((const uint4*)f1)[(size_t)g*512 + t*2 + 1];
        const int row = t >> 1, col = (t & 1) * 16;
        *(uint4*)&xs16[row*72 + col]     = v0;
        *(uint4*)&xs16[row*72 + col + 8] = v1;
    }
    for (int i = t; i < 128*29; i += 256) {   // zero cols 35..63 (only K<64 is read)
        const int r = i / 29, c = 35 + (i - r*29);
        xs16[r*72 + c] = 0;
    }
    if (t < CPG_) {
        const int c2 = idx1[g*CPG_ + t];
        slc[t] = c2 - g*CPG2_;
        #pragma unroll
        for (int d = 0; d < 3; d++)
            xs16[t*72 + 32 + d] = f2bf(pos1[(g*CPG_ + t)*3 + d] - pos2[c2*3 + d]);
    }
    __syncthreads();

    // P1: local conv MFMA (wave wv owns channels wv*16+lr); also scatter S^T ones + int counts
    float hv[8][4];
    {
        const int chn = wv*16 + lr;
        const bf16x8 bw0 = *(const bf16x8*)&w2lT[chn*64 + quad*8];
        const bf16x8 bw1 = *(const bf16x8*)&w2lT[chn*64 + 32 + quad*8];
        const float bias = b2l[chn];
        #pragma unroll
        for (int m = 0; m < 8; m++) {
            f32x4 acc = (f32x4){bias, bias, bias, bias};
            const bf16x8 a0 = *(const bf16x8*)&xs16[(m*16 + lr)*72 + quad*8];
            const bf16x8 a1 = *(const bf16x8*)&xs16[(m*16 + lr)*72 + 32 + quad*8];
            acc = __builtin_amdgcn_mfma_f32_16x16x32_bf16(a0, bw0, acc, 0, 0, 0);
            acc = __builtin_amdgcn_mfma_f32_16x16x32_bf16(a1, bw1, acc, 0, 0, 0);
            #pragma unroll
            for (int r = 0; r < 4; r++) hv[m][r] = celu_f(acc[r]);
        }
    }
    if (t < CPG_) {
        sT[slc[t]*136 + t] = 0x3F80;          // bf16 1.0 (exact)
        atomicAdd(&cnti[slc[t]], 1);          // native int LDS atomic
    }
    __syncthreads();   // all xs16 reads done; HT overlay becomes live

    // P2: store H^T bf16 (C layout rows e = m*16+quad*4+r are contiguous -> uint2 packs)
    {
        const int chn = wv*16 + lr;
        #pragma unroll
        for (int m = 0; m < 8; m++) {
            uint2 p;
            p.x = (unsigned)f2bf(hv[m][0]) | ((unsigned)f2bf(hv[m][1]) << 16);
            p.y = (unsigned)f2bf(hv[m][2]) | ((unsigned)f2bf(hv[m][3]) << 16);
            *(uint2*)&HT[chn*136 + m*16 + quad*4] = p;
        }
    }
    if (t < CPG2_) invc[t] = 1.f / fmaxf((float)cnti[t], 1.f);
    __syncthreads();

    // P3: segment-sum MFMA: agg[32][64] = S^T[32][128] @ H[128][64]
    float aggv[2][4];
    {
        const int ch = wv*16 + lr;
        f32x4 acc[2];
        acc[0] = (f32x4){0.f, 0.f, 0.f, 0.f};
        acc[1] = (f32x4){0.f, 0.f, 0.f, 0.f};
        #pragma unroll
        for (int ks = 0; ks < 4; ks++) {
            const bf16x8 b = *(const bf16x8*)&HT[ch*136 + ks*32 + quad*8];
            #pragma unroll
            for (int mt = 0; mt < 2; mt++) {
                const bf16x8 a = *(const bf16x8*)&sT[(mt*16 + lr)*136 + ks*32 + quad*8];
                acc[mt] = __builtin_amdgcn_mfma_f32_16x16x32_bf16(a, b, acc[mt], 0, 0, 0);
            }
        }
        #pragma unroll
        for (int mt = 0; mt < 2; mt++)
        #pragma unroll
        for (int r = 0; r < 4; r++) {
            const int s = mt*16 + quad*4 + r;
            aggv[mt][r] = acc[mt][r] * invc[s];
        }
    }
    __syncthreads();   // sT reads done; agg2 overlay becomes live

    // P4: store agg bf16 [s][ch] stride 72
    {
        const int ch = wv*16 + lr;
        #pragma unroll
        for (int mt = 0; mt < 2; mt++)
        #pragma unroll
        for (int r = 0; r < 4; r++)
            agg2[(mt*16 + quad*4 + r)*72 + ch] = f2bf(aggv[mt][r]);
    }
    __syncthreads();

    // P5: global conv MFMA: [32x64]@[64x128]; wave owns n-tiles {wv, wv+4}
    {
        f32x4 acc2[2][2];
        int   chn2[2];
        bf16x8 bw[2][2];
        #pragma unroll
        for (int nt = 0; nt < 2; nt++) {
            chn2[nt] = (wv + nt*4)*16 + lr;
            const float bias = b2g[chn2[nt]];
            #pragma unroll
            for (int mt = 0; mt < 2; mt++) acc2[nt][mt] = (f32x4){bias, bias, bias, bias};
            bw[nt][0] = *(const bf16x8*)&w2gT[chn2[nt]*64 + quad*8];
            bw[nt][1] = *(const bf16x8*)&w2gT[chn2[nt]*64 + 32 + quad*8];
        }
        #pragma unroll
        for (int ks = 0; ks < 2; ks++) {
            #pragma unroll
            for (int mt = 0; mt < 2; mt++) {
                const bf16x8 a = *(const bf16x8*)&agg2[(mt*16 + lr)*72 + ks*32 + quad*8];
                acc2[0][mt] = __builtin_amdgcn_mfma_f32_16x16x32_bf16(a, bw[0][ks], acc2[0][mt], 0, 0, 0);
                acc2[1][mt] = __builtin_amdgcn_mfma_f32_16x16x32_bf16(a, bw[1][ks], acc2[1][mt], 0, 0, 0);
            }
        }
        #pragma unroll
        for (int nt = 0; nt < 2; nt++)
        #pragma unroll
        for (int mt = 0; mt < 2; mt++)
        #pragma unroll
        for (int r = 0; r < 4; r++) {
            const int row = mt*16 + quad*4 + r;
            f2[(size_t)(g*CPG2_ + row)*128 + chn2[nt]] = f2bf(celu_f(acc2[nt][mt][r]));
        }
    }
}

// ---------------- conv3 (MFMA local) + gemvs + sample: 2 glimpses per block (unchanged) ----------------
__global__ __launch_bounds__(256, 4) void k_conv3(
    const unsigned short* __restrict__ f2, const float* __restrict__ pos2,
    const unsigned short* __restrict__ w3lT, const float* __restrict__ b3l,
    const float* __restrict__ W3g, const float* __restrict__ b3g,
    const float* __restrict__ Wlin, const float* __restrict__ blin,
    const float* __restrict__ eps, float* __restrict__ out)
{
    const int g0 = blockIdx.x * 2, t = threadIdx.x;
    const int lane = t & 63, wv = t >> 6;
    const int lr = lane & 15, quad = lane >> 4;
    __shared__ __align__(16) unsigned short xs16[64*168];
    __shared__ float red2[2*128*9];
    __shared__ float agg[256];
    __shared__ float f3s[512];
    __shared__ float outs[512];

    {
        const int row = t >> 2, q = t & 3;
        const size_t base = (size_t)(g0*CPG2_ + row)*16 + q*4;
        const uint4 v0 = ((const uint4*)f2)[base + 0];
        const uint4 v1 = ((const uint4*)f2)[base + 1];
        const uint4 v2 = ((const uint4*)f2)[base + 2];
        const uint4 v3 = ((const uint4*)f2)[base + 3];
        *(uint4*)&xs16[row*168 + q*32]      = v0;
        *(uint4*)&xs16[row*168 + q*32 + 8]  = v1;
        *(uint4*)&xs16[row*168 + q*32 + 16] = v2;
        *(uint4*)&xs16[row*168 + q*32 + 24] = v3;
    }
    for (int i = t; i < 64*29; i += 256) {   // zero cols 131..159 (K reads stop at 159)
        const int r = i / 29, c = 131 + (i - r*29);
        xs16[r*168 + c] = 0;
    }
    if (t < 64) {
        #pragma unroll
        for (int d = 0; d < 3; d++)
            xs16[t*168 + 128 + d] = f2bf(pos2[(g0*CPG2_ + t)*3 + d]);
    }
    __syncthreads();

    {
        f32x4 acc[2][4];
        int chn[2];
        #pragma unroll
        for (int nt = 0; nt < 2; nt++) {
            chn[nt] = (wv + nt*4)*16 + lr;
            const float bias = b3l[chn[nt]];
            #pragma unroll
            for (int mt = 0; mt < 4; mt++) acc[nt][mt] = (f32x4){bias, bias, bias, bias};
        }
        #pragma unroll
        for (int ks = 0; ks < 5; ks++) {
            const bf16x8 b0 = *(const bf16x8*)&w3lT[chn[0]*160 + ks*32 + quad*8];
            const bf16x8 b1 = *(const bf16x8*)&w3lT[chn[1]*160 + ks*32 + quad*8];
            #pragma unroll
            for (int mt = 0; mt < 4; mt++) {
                const bf16x8 a = *(const bf16x8*)&xs16[(mt*16 + lr)*168 + ks*32 + quad*8];
                acc[0][mt] = __builtin_amdgcn_mfma_f32_16x16x32_bf16(a, b0, acc[0][mt], 0, 0, 0);
                acc[1][mt] = __builtin_amdgcn_mfma_f32_16x16x32_bf16(a, b1, acc[1][mt], 0, 0, 0);
            }
        }
        #pragma unroll
        for (int nt = 0; nt < 2; nt++)
        #pragma unroll
        for (int mt = 0; mt < 4; mt++) {
            float p = celu_f(acc[nt][mt][0]) + celu_f(acc[nt][mt][1])
                    + celu_f(acc[nt][mt][2]) + celu_f(acc[nt][mt][3]);
            const int gl = mt >> 1, pidx = (mt & 1)*4 + quad;
            red2[(gl*128 + chn[nt])*9 + pidx] = p;
        }
    }
    __syncthreads();
    {
        const int gl = t >> 7, ch = t & 127;
        const float* rp = &red2[(gl*128 + ch)*9];
        float a = 0.f;
        #pragma unroll
        for (int p = 0; p < 8; p++) a += rp[p];
        agg[gl*128 + ch] = a * (1.f/32.f);
    }
    __syncthreads();

    {
        float a0 = b3g[t], a1 = a0;
        #pragma unroll 2
        for (int k = 0; k < 128; k += 4) {
            const float4 ga = *(const float4*)&agg[k];
            const float4 gb = *(const float4*)&agg[128 + k];
            const float w0 = W3g[(k+0)*256+t], w1 = W3g[(k+1)*256+t];
            const float w2 = W3g[(k+2)*256+t], w3 = W3g[(k+3)*256+t];
            a0 += ga.x*w0 + ga.y*w1 + ga.z*w2 + ga.w*w3;
            a1 += gb.x*w0 + gb.y*w1 + gb.z*w2 + gb.w*w3;
        }
        f3s[t]       = celu_f(a0);
        f3s[256 + t] = celu_f(a1);
    }
    __syncthreads();

    {
        float a0 = blin[t], a1 = a0;
        #pragma unroll 2
        for (int k = 0; k < 256; k += 4) {
            const float4 fa = *(const float4*)&f3s[k];
            const float4 fb = *(const float4*)&f3s[256 + k];
            const float w0 = Wlin[(k+0)*256+t], w1 = Wlin[(k+1)*256+t];
            const float w2 = Wlin[(k+2)*256+t], w3 = Wlin[(k+3)*256+t];
            a0 += fa.x*w0 + fa.y*w1 + fa.z*w2 + fa.w*w3;
            a1 += fb.x*w0 + fb.y*w1 + fb.z*w2 + fb.w*w3;
        }
        outs[t]       = a0;
        outs[256 + t] = a1;
    }
    out[OFF_F + (size_t)g0*256 + t]     = f3s[t];
    out[OFF_F + (size_t)(g0+1)*256 + t] = f3s[256 + t];
    __syncthreads();

    if (t < 128) {
        #pragma unroll
        for (int gl = 0; gl < 2; gl++) {
            const int g = g0 + gl;
            const float mu    = outs[gl*256 + t];
            const float sigma = softplus_f(outs[gl*256 + 128 + t]);
            const float z     = mu + sigma * eps[g*128 + t];
            out[OFF_MU + g*128 + t] = mu;
            out[OFF_SG + g*128 + t] = sigma;
            if (t < 64) out[OFF_ZW + g*64 + t] = z;
            else        out[OFF_ZM + g*64 + (t - 64)] = z;
        }
    }
}

extern "C" void kernel_launch(void* const* d_in, const int* in_sizes, int n_in,
                              void* d_out, int out_size, void* d_ws, size_t ws_size,
                              hipStream_t stream)
{
    const float* rgb  = (const float*)d_in[0];
    const float* pos  = (const float*)d_in[1];
    const float* pos1 = (const float*)d_in[2];
    const float* pos2 = (const float*)d_in[3];
    const int*   idx0 = (const int*)d_in[4];
    const int*   idx1 = (const int*)d_in[5];
    const float* eps  = (const float*)d_in[7];
    const float* W1l = (const float*)d_in[8],  *b1l = (const float*)d_in[9];
    const float* W1g = (const float*)d_in[10], *b1g = (const float*)d_in[11];
    const float* W2l = (const float*)d_in[12], *b2l = (const float*)d_in[13];
    const float* W2g = (const float*)d_in[14], *b2g = (const float*)d_in[15];
    const float* W3l = (const float*)d_in[16], *b3l = (const float*)d_in[17];
    const float* W3g = (const float*)d_in[18], *b3g = (const float*)d_in[19];
    const float* Wlin = (const float*)d_in[20], *blin = (const float*)d_in[21];

    unsigned short* f1   = (unsigned short*)d_ws;        // M1*32 bf16
    unsigned short* f2   = f1 + (size_t)M1_*32;          // M2*128 bf16
    unsigned short* w2lT = f2 + (size_t)M2_*128;         // 64*64
    unsigned short* w2gT = w2lT + 64*64;                 // 128*64
    unsigned short* w3lT = w2gT + 128*64;                // 128*160
    float* outp = (float*)d_out;

    k_prep <<<32,   256, 0, stream>>>(W2l, W2g, W3l, w2lT, w2gT, w3lT);
    k_conv1<<<G_,   256, 0, stream>>>(rgb, pos, pos1, idx0, W1l, b1l, W1g, b1g, f1);
    k_conv2<<<G_,   256, 0, stream>>>(f1, pos1, pos2, idx1, w2lT, b2l, w2gT, b2g, f2);
    k_conv3<<<G_/2, 256, 0, stream>>>(f2, pos2, w3lT, b3l, W3g, b3g, Wlin, blin, eps, outp);
}